// Round 4
// baseline (3448.795 us; speedup 1.0000x reference)
//
#include <hip/hip_runtime.h>
#include <math.h>

#define NB       8
#define SEQ      8192
#define L1OUT    2048
#define LOUT     1024
#define DMODEL   256
#define DINNER   1024
#define NHEADS   16
#define HEADDIM  64
#define DSTATE   64
#define CONVDIM  1152
#define DINPROJ  2192
#define NPADIN   2304     // in_proj rows padded to multiple of 128
#define NLAYERS  8

typedef _Float16 f16;
typedef __attribute__((ext_vector_type(8))) _Float16 f16x8;
typedef __attribute__((ext_vector_type(4))) _Float16 f16x4;
typedef __attribute__((ext_vector_type(4))) float    f32x4;

__device__ __forceinline__ float gelu_f(float v) {
    return 0.5f * v * (1.0f + erff(v * 0.70710678118654752f));
}
__device__ __forceinline__ float silu_f(float v) {
    return v / (1.0f + expf(-v));
}

__device__ __forceinline__ void gload16(const void* g, void* l) {
    __builtin_amdgcn_global_load_lds(
        (const __attribute__((address_space(1))) unsigned int*)g,
        (__attribute__((address_space(3))) unsigned int*)l, 16, 0, 0);
}

// ---------------- weight casts ----------------
__global__ __launch_bounds__(256) void k_cast(const float* __restrict__ in,
                                              f16* __restrict__ out, int n) {
    int i = blockIdx.x * 256 + threadIdx.x;
    if (i < n) out[i] = (f16)in[i];
}

// in_proj: [8][2192][256] fp32 -> [8][2304][256] f16, zero-padded rows
__global__ __launch_bounds__(256) void k_cast_inproj(const float* __restrict__ w,
                                                     f16* __restrict__ out) {
    int idx = blockIdx.x * 256 + threadIdx.x;       // 8*2304*256
    int c = idx & 255;
    int r = (idx >> 8) % NPADIN;
    int l = idx / (NPADIN * 256);
    float v = (r < DINPROJ) ? w[((size_t)l * DINPROJ + r) * 256 + c] : 0.f;
    out[idx] = (f16)v;
}

// ---------------- conv1 (3->64, k16, s4, pad6) + GELU ----------------
__global__ __launch_bounds__(256) void k_conv1(const float* __restrict__ x,
                                               const float* __restrict__ w,
                                               const float* __restrict__ bias,
                                               float* __restrict__ out) {
    int idx = blockIdx.x * 256 + threadIdx.x;      // NB*64*L1OUT
    int t  = idx & (L1OUT - 1);
    int co = (idx >> 11) & 63;
    int b  = idx >> 17;
    float s = bias[co];
#pragma unroll
    for (int ci = 0; ci < 3; ++ci) {
        const float* xp = x + ((size_t)b * 3 + ci) * SEQ;
        const float* wp = w + (co * 3 + ci) * 16;
#pragma unroll
        for (int k = 0; k < 16; ++k) {
            int pos = t * 4 + k - 6;
            if (pos >= 0 && pos < SEQ) s = fmaf(xp[pos], wp[k], s);
        }
    }
    out[idx] = gelu_f(s);
}

// ---------------- im2col for conv2 (64ch, k16, s2, pad7) -> f16 ----------------
__global__ __launch_bounds__(256) void k_im2col(const float* __restrict__ h1,
                                                f16* __restrict__ A) {
    int idx = blockIdx.x * 256 + threadIdx.x;      // 8192*1024
    int col = idx & 1023;
    int row = idx >> 10;
    int t = row & (LOUT - 1);
    int b = row >> 10;
    int ci = col >> 4, k = col & 15;
    int pos = t * 2 + k - 7;
    float v = 0.f;
    if (pos >= 0 && pos < L1OUT) v = h1[((size_t)b * 64 + ci) * L1OUT + pos];
    A[idx] = (f16)v;
}

// ---------------- fp16 MFMA GEMM: C[M,N] = A[M,K] * B[Npad,K]^T ----------------
template<int BM, int EPI>
__global__ __launch_bounds__(256) void k_hgemm(const f16* __restrict__ A,
                                               const f16* __restrict__ Bw,
                                               float* __restrict__ Cf,
                                               f16* __restrict__ Ch,
                                               int M, int N, int K,
                                               const float* __restrict__ bias) {
    constexpr int MI = BM / 32;
    __shared__ f16 As[BM * 32];
    __shared__ f16 Bs[128 * 32];
    int tid  = threadIdx.x;
    int lane = tid & 63, wid = tid >> 6;
    int wm = wid >> 1, wn = wid & 1;
    int row0 = blockIdx.y * BM, col0 = blockIdx.x * 128;
    int lr = lane & 15, kb = lane >> 4;

    f32x4 acc[MI][4];
#pragma unroll
    for (int mi = 0; mi < MI; ++mi)
#pragma unroll
        for (int ni = 0; ni < 4; ++ni)
            acc[mi][ni] = (f32x4){0.f, 0.f, 0.f, 0.f};

    int srow = tid >> 2;
    int scol = (tid & 3) * 8;

    for (int k0 = 0; k0 < K; k0 += 32) {
        __syncthreads();
#pragma unroll
        for (int is = 0; is < BM / 64; ++is)
            gload16(A + (size_t)(row0 + is * 64 + srow) * K + k0 + scol,
                    &As[is * 2048 + wid * 512]);
#pragma unroll
        for (int is = 0; is < 2; ++is)
            gload16(Bw + (size_t)(col0 + is * 64 + srow) * K + k0 + scol,
                    &Bs[is * 2048 + wid * 512]);
        __syncthreads();

        f16x8 a[MI], b[4];
#pragma unroll
        for (int mi = 0; mi < MI; ++mi)
            a[mi] = *reinterpret_cast<const f16x8*>(
                &As[(wm * (BM / 2) + mi * 16 + lr) * 32 + kb * 8]);
#pragma unroll
        for (int ni = 0; ni < 4; ++ni)
            b[ni] = *reinterpret_cast<const f16x8*>(
                &Bs[(wn * 64 + ni * 16 + lr) * 32 + kb * 8]);
#pragma unroll
        for (int mi = 0; mi < MI; ++mi)
#pragma unroll
            for (int ni = 0; ni < 4; ++ni)
                acc[mi][ni] = __builtin_amdgcn_mfma_f32_16x16x32_f16(
                    a[mi], b[ni], acc[mi][ni], 0, 0, 0);
    }

#pragma unroll
    for (int mi = 0; mi < MI; ++mi)
#pragma unroll
        for (int ni = 0; ni < 4; ++ni) {
            int ccol = col0 + wn * 64 + ni * 16 + lr;
            if (ccol < N) {
                int rbase = row0 + wm * (BM / 2) + mi * 16 + kb * 4;
                f32x4 v = acc[mi][ni];
#pragma unroll
                for (int r = 0; r < 4; ++r) {
                    float val = v[r];
                    if (EPI == 1) val = gelu_f(val + bias[ccol]);
                    if (Cf) Cf[(size_t)(rbase + r) * N + ccol] = val;
                    if (Ch) Ch[(size_t)(rbase + r) * N + ccol] = (f16)val;
                }
            }
        }
}

// ------- depthwise causal conv (k=4) + SiLU; fp32 out + f16 shadow out -------
__global__ __launch_bounds__(256) void k_dwconv(const float* __restrict__ zx,
                                                const float* __restrict__ w,
                                                const float* __restrict__ bias,
                                                float* __restrict__ out,
                                                f16* __restrict__ out16) {
    int idx = blockIdx.x * 256 + threadIdx.x;      // NB*LOUT*CONVDIM
    int c  = idx % CONVDIM;
    int bl = idx / CONVDIM;
    int l  = bl & (LOUT - 1);
    const float* wp = w + c * 4;
    float s = bias[c];
#pragma unroll
    for (int k = 0; k < 4; ++k) {
        int t = l - 3 + k;
        if (t >= 0) s = fmaf(zx[(size_t)(bl - 3 + k) * DINPROJ + DINNER + c], wp[k], s);
    }
    float v = silu_f(s);
    out[idx] = v;
    out16[idx] = (f16)v;
}

// -------- dadt[bl,h] = (exp(-exp(A_log)*dt), dt) interleaved float2 --------
__global__ __launch_bounds__(256) void k_dt(const float* __restrict__ zx,
                                            const float* __restrict__ dt_bias,
                                            const float* __restrict__ A_log,
                                            float* __restrict__ dadt) {
    int idx = blockIdx.x * 256 + threadIdx.x;      // NB*LOUT*NHEADS
    int hh = idx & 15;
    int bl = idx >> 4;
    float raw = zx[(size_t)bl * DINPROJ + DINNER + CONVDIM + hh] + dt_bias[hh];
    float dtv = (raw > 20.f) ? raw : log1pf(expf(raw));
    float dav = expf(-expf(A_log[hh]) * dtv);
    *(float2*)&dadt[(size_t)idx * 2] = make_float2(dav, dtv);
}

// ---------------- selective scan: no LDS, f16 B/C, 16-step pipeline ----------
// grid: 1024 blocks of 64 threads (1 wave).
// bid: unit = bid&127 -> (b = unit>>4, hh = unit&15); pq = bid>>7 (same-XCD
// replicas: bids sharing (b,h) differ by 128, 128%8==0 -> same XCD L2).
// lane: pr = tid>>3 -> p = pq*8+pr ; ng = tid&7 -> n in [ng*8, ng*8+8)
__global__ __launch_bounds__(64) void k_scan(const f16* __restrict__ bc,
                                             const float* __restrict__ xbc,
                                             const float* __restrict__ dadt,
                                             float* __restrict__ yout) {
    int tid = threadIdx.x;
    int bid = blockIdx.x;
    int unit = bid & 127, pq = bid >> 7;
    int hh = unit & 15, b = unit >> 4;
    int pr = tid >> 3, ng = tid & 7;
    size_t base = (size_t)b * LOUT;

    const f16*   pB = bc + base * CONVDIM + DINNER + ng * 8;
    const f16*   pC = pB + DSTATE;
    const float* pX = xbc + base * CONVDIM + hh * 64 + pq * 8 + pr;
    const float* pA = dadt + (base * NHEADS + hh) * 2;
    float* pY = yout + base * DINNER + hh * 64 + pq * 8 + pr;

    float h[8];
#pragma unroll
    for (int j = 0; j < 8; ++j) h[j] = 0.f;

    f16x8  vB[2][8], vC[2][8];
    float  vX[2][8];
    float2 vA[2][8];

#define LOADG(BUF, G)                                                        \
    {                                                                        \
        _Pragma("unroll")                                                    \
        for (int s = 0; s < 8; ++s) {                                        \
            int t = (G) * 8 + s;                                             \
            size_t r = (size_t)t * CONVDIM;                                  \
            vB[BUF][s] = *(const f16x8*)(pB + r);                            \
            vC[BUF][s] = *(const f16x8*)(pC + r);                            \
            vX[BUF][s] = pX[r];                                              \
            vA[BUF][s] = *(const float2*)(pA + (size_t)t * NHEADS * 2);      \
        }                                                                    \
    }

#define COMPG(BUF, G)                                                        \
    {                                                                        \
        _Pragma("unroll")                                                    \
        for (int s = 0; s < 8; ++s) {                                        \
            float dAv = vA[BUF][s].x, dtv = vA[BUF][s].y;                    \
            float cc = dtv * vX[BUF][s];                                     \
            float ys = 0.f;                                                  \
            _Pragma("unroll")                                                \
            for (int j = 0; j < 8; ++j) {                                    \
                h[j] = fmaf(h[j], dAv, cc * (float)vB[BUF][s][j]);           \
                ys = fmaf(h[j], (float)vC[BUF][s][j], ys);                   \
            }                                                                \
            ys += __shfl_xor(ys, 1);                                         \
            ys += __shfl_xor(ys, 2);                                         \
            ys += __shfl_xor(ys, 4);                                         \
            if (ng == 0) pY[(size_t)((G) * 8 + s) * DINNER] = ys;            \
        }                                                                    \
    }

    LOADG(0, 0);
    for (int g = 0; g < 128; g += 2) {
        LOADG(1, g + 1);
        COMPG(0, g);
        if (g + 2 < 128) LOADG(0, g + 2);
        COMPG(1, g + 1);
    }
#undef LOADG
#undef COMPG
}

// ------ y = (yss + D*xh) * silu(z); RMSNorm * rms_w; write f16 for out_proj ----
__global__ __launch_bounds__(256) void k_gate(const float* __restrict__ zx,
                                              const float* __restrict__ xbc,
                                              const float* __restrict__ ssmD,
                                              const float* __restrict__ rmsw,
                                              const float* __restrict__ y,
                                              f16* __restrict__ ygate) {
    __shared__ float sh[4];
    int bl = blockIdx.x, tid = threadIdx.x;
    int c = tid * 4;
    float4 ys = *reinterpret_cast<const float4*>(&y[(size_t)bl * DINNER + c]);
    float4 xh = *reinterpret_cast<const float4*>(&xbc[(size_t)bl * CONVDIM + c]);
    float4 z4 = *reinterpret_cast<const float4*>(&zx[(size_t)bl * DINPROJ + c]);
    float Dv = ssmD[tid >> 4];
    float v[4] = {ys.x, ys.y, ys.z, ys.w};
    float xv[4] = {xh.x, xh.y, xh.z, xh.w};
    float zv[4] = {z4.x, z4.y, z4.z, z4.w};
    float ss = 0.f;
#pragma unroll
    for (int j = 0; j < 4; ++j) {
        v[j] = (v[j] + Dv * xv[j]) * silu_f(zv[j]);
        ss += v[j] * v[j];
    }
    int lane = tid & 63, wid = tid >> 6;
#pragma unroll
    for (int o = 32; o > 0; o >>= 1) ss += __shfl_down(ss, o, 64);
    if (lane == 0) sh[wid] = ss;
    __syncthreads();
    float total = sh[0] + sh[1] + sh[2] + sh[3];
    float r = rsqrtf(total * (1.f / DINNER) + 1e-5f);
    f16x4 o4;
    o4.x = (f16)(v[0] * r * rmsw[c + 0]);
    o4.y = (f16)(v[1] * r * rmsw[c + 1]);
    o4.z = (f16)(v[2] * r * rmsw[c + 2]);
    o4.w = (f16)(v[3] * r * rmsw[c + 3]);
    *reinterpret_cast<f16x4*>(&ygate[(size_t)bl * DINNER + c]) = o4;
}

// ---------------- final LayerNorm + mean pool (atomics) ----------------
__global__ __launch_bounds__(256) void k_lnpool(const float* __restrict__ h,
                                                const float* __restrict__ lnw,
                                                const float* __restrict__ lnb,
                                                float* __restrict__ pooled) {
    __shared__ float sh1[4], sh2[4];
    int bl = blockIdx.x, c = threadIdx.x;
    float v = h[(size_t)bl * DMODEL + c];
    float s1 = v, s2 = v * v;
    int lane = c & 63, wid = c >> 6;
#pragma unroll
    for (int o = 32; o > 0; o >>= 1) {
        s1 += __shfl_down(s1, o, 64);
        s2 += __shfl_down(s2, o, 64);
    }
    if (lane == 0) { sh1[wid] = s1; sh2[wid] = s2; }
    __syncthreads();
    float t1 = sh1[0] + sh1[1] + sh1[2] + sh1[3];
    float t2 = sh2[0] + sh2[1] + sh2[2] + sh2[3];
    float mu = t1 * (1.f / DMODEL);
    float var = t2 * (1.f / DMODEL) - mu * mu;
    float o = (v - mu) * rsqrtf(var + 1e-5f) * lnw[c] + lnb[c];
    atomicAdd(&pooled[(bl >> 10) * DMODEL + c], o * (1.f / LOUT));
}

__global__ void k_zero(float* __restrict__ p, int n) {
    int i = blockIdx.x * 256 + threadIdx.x;
    if (i < n) p[i] = 0.f;
}

// ---------------- regression head ----------------
__global__ __launch_bounds__(128) void k_head(const float* __restrict__ pooled,
                                              const float* __restrict__ w1,
                                              const float* __restrict__ b1,
                                              const float* __restrict__ w2,
                                              const float* __restrict__ b2,
                                              float* __restrict__ out) {
    __shared__ float red[2];
    int b = blockIdx.x, j = threadIdx.x;
    float acc = b1[j];
#pragma unroll 8
    for (int d = 0; d < DMODEL; ++d)
        acc = fmaf(pooled[b * DMODEL + d], w1[j * DMODEL + d], acc);
    float r = gelu_f(acc) * w2[j];
#pragma unroll
    for (int o = 32; o > 0; o >>= 1) r += __shfl_down(r, o, 64);
    int lane = j & 63, wid = j >> 6;
    if (lane == 0) red[wid] = r;
    __syncthreads();
    if (j == 0) out[b] = red[0] + red[1] + b2[0];
}

extern "C" void kernel_launch(void* const* d_in, const int* in_sizes, int n_in,
                              void* d_out, int out_size, void* d_ws, size_t ws_size,
                              hipStream_t stream) {
    const float* x         = (const float*)d_in[0];
    const float* conv1_w   = (const float*)d_in[1];
    const float* conv1_b   = (const float*)d_in[2];
    const float* conv2_w   = (const float*)d_in[3];
    const float* conv2_b   = (const float*)d_in[4];
    const float* in_proj_w = (const float*)d_in[5];
    const float* dw_w      = (const float*)d_in[6];
    const float* dw_b      = (const float*)d_in[7];
    const float* dt_bias   = (const float*)d_in[8];
    const float* A_log     = (const float*)d_in[9];
    const float* ssm_D     = (const float*)d_in[10];
    const float* rms_w     = (const float*)d_in[11];
    const float* out_proj_w= (const float*)d_in[12];
    const float* ln_w      = (const float*)d_in[13];
    const float* ln_b      = (const float*)d_in[14];
    const float* reg1_w    = (const float*)d_in[15];
    const float* reg1_b    = (const float*)d_in[16];
    const float* reg2_w    = (const float*)d_in[17];
    const float* reg2_b    = (const float*)d_in[18];

    float* ws = (float*)d_ws;
    size_t off = 0;
    float* c1buf  = ws + off; off += (size_t)NB * 64 * L1OUT;       // 1,048,576
    float* hbuf   = ws + off; off += (size_t)NB * LOUT * DMODEL;    // 2,097,152
    float* zx     = ws + off; off += (size_t)NB * LOUT * DINPROJ;   // 17,956,864
    float* xbcc   = ws + off; off += (size_t)NB * LOUT * CONVDIM;   // 9,437,184
    float* dadt   = ws + off; off += (size_t)NB * LOUT * NHEADS * 2;// 262,144
    float* yss    = ws + off; off += (size_t)NB * LOUT * DINNER;    // 8,388,608
    float* pooled = ws + off; off += NB * DMODEL;                   // 2,048

    f16* fbase = (f16*)(ws + off);
    size_t foff = 0;
    f16* hbf0   = fbase + foff; foff += (size_t)NB * LOUT * DMODEL;
    f16* hbf1   = fbase + foff; foff += (size_t)NB * LOUT * DMODEL;
    f16* ygate  = fbase + foff; foff += (size_t)NB * LOUT * DINNER;
    f16* xbc16  = fbase + foff; foff += (size_t)NB * LOUT * CONVDIM;
    f16* w_in_h = fbase + foff; foff += (size_t)NLAYERS * NPADIN * DMODEL;
    f16* w_out_h= fbase + foff; foff += (size_t)NLAYERS * DMODEL * DINNER;
    f16* w_c2_h = fbase + foff; foff += (size_t)DMODEL * 1024;
    f16* im2h   = (f16*)yss;   // aliased: im2col dead before yss is first written

    // weight casts
    k_cast_inproj<<<(NLAYERS * NPADIN * 256) / 256, 256, 0, stream>>>(in_proj_w, w_in_h);
    k_cast<<<(NLAYERS * DMODEL * DINNER) / 256, 256, 0, stream>>>(
        out_proj_w, w_out_h, NLAYERS * DMODEL * DINNER);
    k_cast<<<(DMODEL * 1024) / 256, 256, 0, stream>>>(conv2_w, w_c2_h, DMODEL * 1024);

    // front-end convs
    k_conv1<<<(NB * 64 * L1OUT) / 256, 256, 0, stream>>>(x, conv1_w, conv1_b, c1buf);
    k_im2col<<<(NB * LOUT * 1024) / 256, 256, 0, stream>>>(c1buf, im2h);
    {
        dim3 g(256 / 128, 8192 / 64);
        k_hgemm<64, 1><<<g, 256, 0, stream>>>(im2h, w_c2_h, nullptr, hbf0,
                                              8192, 256, 1024, conv2_b);
    }

    f16* hcur = hbf0;
    f16* hnxt = hbf1;
    for (int i = 0; i < NLAYERS; ++i) {
        {
            dim3 g(NPADIN / 128, 8192 / 128);
            k_hgemm<128, 0><<<g, 256, 0, stream>>>(
                hcur, w_in_h + (size_t)i * NPADIN * DMODEL, zx, nullptr,
                8192, DINPROJ, DMODEL, nullptr);
        }
        k_dwconv<<<(NB * LOUT * CONVDIM) / 256, 256, 0, stream>>>(
            zx, dw_w + (size_t)i * CONVDIM * 4, dw_b + (size_t)i * CONVDIM,
            xbcc, xbc16);
        k_dt<<<(NB * LOUT * NHEADS) / 256, 256, 0, stream>>>(
            zx, dt_bias + i * NHEADS, A_log + i * NHEADS, dadt);
        k_scan<<<NB * NHEADS * 8, 64, 0, stream>>>(xbc16, xbcc, dadt, yss);
        k_gate<<<NB * LOUT, 256, 0, stream>>>(zx, xbcc, ssm_D + i * NHEADS,
                                              rms_w + (size_t)i * DINNER, yss, ygate);
        {
            dim3 g(DMODEL / 128, 8192 / 64);
            k_hgemm<64, 0><<<g, 256, 0, stream>>>(
                ygate, w_out_h + (size_t)i * DMODEL * DINNER, hbuf, hnxt,
                8192, DMODEL, DINNER, nullptr);
        }
        f16* tmp = hcur; hcur = hnxt; hnxt = tmp;
    }

    // final LN + pool + head
    k_zero<<<(NB * DMODEL + 255) / 256, 256, 0, stream>>>(pooled, NB * DMODEL);
    k_lnpool<<<NB * LOUT, 256, 0, stream>>>(hbuf, ln_w, ln_b, pooled);
    k_head<<<NB, 128, 0, stream>>>(pooled, reg1_w, reg1_b, reg2_w, reg2_b, (float*)d_out);
}

// Round 5
// 1585.892 us; speedup vs baseline: 2.1747x; 2.1747x over previous
//
#include <hip/hip_runtime.h>
#include <math.h>

#define NB       8
#define SEQ      8192
#define L1OUT    2048
#define LOUT     1024
#define DMODEL   256
#define DINNER   1024
#define NHEADS   16
#define HEADDIM  64
#define DSTATE   64
#define CONVDIM  1152
#define DINPROJ  2192
#define NPADIN   2304     // in_proj rows padded to multiple of 128
#define NLAYERS  8
#define NCHUNK   16
#define Q        64       // chunk length

typedef _Float16 f16;
typedef __attribute__((ext_vector_type(8))) _Float16 f16x8;
typedef __attribute__((ext_vector_type(4))) _Float16 f16x4;
typedef __attribute__((ext_vector_type(4))) float    f32x4;

__device__ __forceinline__ float gelu_f(float v) {
    return 0.5f * v * (1.0f + erff(v * 0.70710678118654752f));
}
__device__ __forceinline__ float silu_f(float v) {
    return v / (1.0f + expf(-v));
}

__device__ __forceinline__ void gload16(const void* g, void* l) {
    __builtin_amdgcn_global_load_lds(
        (const __attribute__((address_space(1))) unsigned int*)g,
        (__attribute__((address_space(3))) unsigned int*)l, 16, 0, 0);
}

// ---------------- weight casts ----------------
__global__ __launch_bounds__(256) void k_cast(const float* __restrict__ in,
                                              f16* __restrict__ out, int n) {
    int i = blockIdx.x * 256 + threadIdx.x;
    if (i < n) out[i] = (f16)in[i];
}

__global__ __launch_bounds__(256) void k_cast_inproj(const float* __restrict__ w,
                                                     f16* __restrict__ out) {
    int idx = blockIdx.x * 256 + threadIdx.x;       // 8*2304*256
    int c = idx & 255;
    int r = (idx >> 8) % NPADIN;
    int l = idx / (NPADIN * 256);
    float v = (r < DINPROJ) ? w[((size_t)l * DINPROJ + r) * 256 + c] : 0.f;
    out[idx] = (f16)v;
}

// ---------------- conv1 (3->64, k16, s4, pad6) + GELU ----------------
__global__ __launch_bounds__(256) void k_conv1(const float* __restrict__ x,
                                               const float* __restrict__ w,
                                               const float* __restrict__ bias,
                                               float* __restrict__ out) {
    int idx = blockIdx.x * 256 + threadIdx.x;      // NB*64*L1OUT
    int t  = idx & (L1OUT - 1);
    int co = (idx >> 11) & 63;
    int b  = idx >> 17;
    float s = bias[co];
#pragma unroll
    for (int ci = 0; ci < 3; ++ci) {
        const float* xp = x + ((size_t)b * 3 + ci) * SEQ;
        const float* wp = w + (co * 3 + ci) * 16;
#pragma unroll
        for (int k = 0; k < 16; ++k) {
            int pos = t * 4 + k - 6;
            if (pos >= 0 && pos < SEQ) s = fmaf(xp[pos], wp[k], s);
        }
    }
    out[idx] = gelu_f(s);
}

// ---------------- im2col for conv2 (64ch, k16, s2, pad7) -> f16 ----------------
__global__ __launch_bounds__(256) void k_im2col(const float* __restrict__ h1,
                                                f16* __restrict__ A) {
    int idx = blockIdx.x * 256 + threadIdx.x;      // 8192*1024
    int col = idx & 1023;
    int row = idx >> 10;
    int t = row & (LOUT - 1);
    int b = row >> 10;
    int ci = col >> 4, k = col & 15;
    int pos = t * 2 + k - 7;
    float v = 0.f;
    if (pos >= 0 && pos < L1OUT) v = h1[((size_t)b * 64 + ci) * L1OUT + pos];
    A[idx] = (f16)v;
}

// ---------------- fp16 MFMA GEMM: C[M,N] = A[M,K] * B[Npad,K]^T ----------------
template<int BM, int EPI>
__global__ __launch_bounds__(256) void k_hgemm(const f16* __restrict__ A,
                                               const f16* __restrict__ Bw,
                                               float* __restrict__ Cf,
                                               f16* __restrict__ Ch,
                                               int M, int N, int K,
                                               const float* __restrict__ bias) {
    constexpr int MI = BM / 32;
    __shared__ f16 As[BM * 32];
    __shared__ f16 Bs[128 * 32];
    int tid  = threadIdx.x;
    int lane = tid & 63, wid = tid >> 6;
    int wm = wid >> 1, wn = wid & 1;
    int row0 = blockIdx.y * BM, col0 = blockIdx.x * 128;
    int lr = lane & 15, kb = lane >> 4;

    f32x4 acc[MI][4];
#pragma unroll
    for (int mi = 0; mi < MI; ++mi)
#pragma unroll
        for (int ni = 0; ni < 4; ++ni)
            acc[mi][ni] = (f32x4){0.f, 0.f, 0.f, 0.f};

    int srow = tid >> 2;
    int scol = (tid & 3) * 8;

    for (int k0 = 0; k0 < K; k0 += 32) {
        __syncthreads();
#pragma unroll
        for (int is = 0; is < BM / 64; ++is)
            gload16(A + (size_t)(row0 + is * 64 + srow) * K + k0 + scol,
                    &As[is * 2048 + wid * 512]);
#pragma unroll
        for (int is = 0; is < 2; ++is)
            gload16(Bw + (size_t)(col0 + is * 64 + srow) * K + k0 + scol,
                    &Bs[is * 2048 + wid * 512]);
        __syncthreads();

        f16x8 a[MI], b[4];
#pragma unroll
        for (int mi = 0; mi < MI; ++mi)
            a[mi] = *reinterpret_cast<const f16x8*>(
                &As[(wm * (BM / 2) + mi * 16 + lr) * 32 + kb * 8]);
#pragma unroll
        for (int ni = 0; ni < 4; ++ni)
            b[ni] = *reinterpret_cast<const f16x8*>(
                &Bs[(wn * 64 + ni * 16 + lr) * 32 + kb * 8]);
#pragma unroll
        for (int mi = 0; mi < MI; ++mi)
#pragma unroll
            for (int ni = 0; ni < 4; ++ni)
                acc[mi][ni] = __builtin_amdgcn_mfma_f32_16x16x32_f16(
                    a[mi], b[ni], acc[mi][ni], 0, 0, 0);
    }

#pragma unroll
    for (int mi = 0; mi < MI; ++mi)
#pragma unroll
        for (int ni = 0; ni < 4; ++ni) {
            int ccol = col0 + wn * 64 + ni * 16 + lr;
            if (ccol < N) {
                int rbase = row0 + wm * (BM / 2) + mi * 16 + kb * 4;
                f32x4 v = acc[mi][ni];
#pragma unroll
                for (int r = 0; r < 4; ++r) {
                    float val = v[r];
                    if (EPI == 1) val = gelu_f(val + bias[ccol]);
                    if (Cf) Cf[(size_t)(rbase + r) * N + ccol] = val;
                    if (Ch) Ch[(size_t)(rbase + r) * N + ccol] = (f16)val;
                }
            }
        }
}

// ------- depthwise causal conv (k=4) + SiLU -> f16 ----------------
__global__ __launch_bounds__(256) void k_dwconv(const float* __restrict__ zx,
                                                const float* __restrict__ w,
                                                const float* __restrict__ bias,
                                                f16* __restrict__ out16) {
    int idx = blockIdx.x * 256 + threadIdx.x;      // NB*LOUT*CONVDIM
    int c  = idx % CONVDIM;
    int bl = idx / CONVDIM;
    int l  = bl & (LOUT - 1);
    const float* wp = w + c * 4;
    float s = bias[c];
#pragma unroll
    for (int k = 0; k < 4; ++k) {
        int t = l - 3 + k;
        if (t >= 0) s = fmaf(zx[(size_t)(bl - 3 + k) * DINPROJ + DINNER + c], wp[k], s);
    }
    out16[idx] = (f16)silu_f(s);
}

// -------- dadt[bl,h] = (ldA, dt) with ldA = -exp(A_log)*dt (log decay) ------
__global__ __launch_bounds__(256) void k_dt(const float* __restrict__ zx,
                                            const float* __restrict__ dt_bias,
                                            const float* __restrict__ A_log,
                                            float* __restrict__ dadt) {
    int idx = blockIdx.x * 256 + threadIdx.x;      // NB*LOUT*NHEADS
    int hh = idx & 15;
    int bl = idx >> 4;
    float raw = zx[(size_t)bl * DINPROJ + DINNER + CONVDIM + hh] + dt_bias[hh];
    float dtv = (raw > 20.f) ? raw : log1pf(expf(raw));
    float lda = -expf(A_log[hh]) * dtv;
    *(float2*)&dadt[(size_t)idx * 2] = make_float2(lda, dtv);
}

// ------- x transpose: x16T[b][h][p][l] from xbc16[b*l][h*64+p] -------
__global__ __launch_bounds__(256) void k_xT(const f16* __restrict__ xbc16,
                                            f16* __restrict__ x16T) {
    __shared__ f16 Tl[64][72];
    int tid = threadIdx.x;
    int bid = blockIdx.x;               // (b*16 + h)*16 + lt
    int lt = bid & 15, h = (bid >> 4) & 15, b = bid >> 8;
    const f16* src = xbc16 + ((size_t)(b * 1024 + lt * 64)) * CONVDIM + h * 64;
#pragma unroll
    for (int it = 0; it < 2; ++it) {
        int cid = it * 256 + tid;
        int r = cid >> 3, sg = (cid & 7) * 8;
        *(f16x8*)&Tl[r][sg] = *(const f16x8*)(src + (size_t)r * CONVDIM + sg);
    }
    __syncthreads();
    f16* dst = x16T + ((size_t)(b * 16 + h) * 64) * 1024 + lt * 64;
#pragma unroll
    for (int it = 0; it < 2; ++it) {
        int cid = it * 256 + tid;
        int p = cid >> 3, ls = (cid & 7) * 8;
        f16x8 v;
#pragma unroll
        for (int j = 0; j < 8; ++j) v[j] = Tl[ls + j][p];
        *(f16x8*)(dst + (size_t)p * 1024 + ls) = v;
    }
}

// ---------------- SSD part 1: per (b, chunk, 4 heads) ----------------
// G = C.B^T (shared), per head: S = X^T.(w*B)^T, Y_intra = M.X  -> yss
__global__ __launch_bounds__(256) void k_ssd1(const f16* __restrict__ xbc16,
                                              const f16* __restrict__ x16T,
                                              const float* __restrict__ dadt,
                                              float* __restrict__ yss,
                                              float* __restrict__ Sbuf,
                                              float* __restrict__ Abuf) {
    __shared__ f16 Bs[64][72];
    __shared__ f16 Cs[64][72];
    __shared__ float GT[64][68];            // GT[s][t]
    __shared__ f16 Mw[4][64][72];           // per wave: sBT then M
    __shared__ float LaW[4][64], dtW[4][64];

    int tid = threadIdx.x, lane = tid & 63, wid = tid >> 6;
    int bid = blockIdx.x;
    int hq = bid & 3, c = (bid >> 2) & 15, b = bid >> 6;
    int h = hq * 4 + wid;
    int lr = lane & 15, kb = lane >> 4;

    // early global loads: X^T fragments (row p, k=t) -- used as A in S and B in Y
    f16x8 xfrag[4][2];
    const f16* xTh = x16T + ((size_t)(b * 16 + h) * 64) * 1024 + c * 64;
#pragma unroll
    for (int pi = 0; pi < 4; ++pi)
#pragma unroll
        for (int ks = 0; ks < 2; ++ks)
            xfrag[pi][ks] = *(const f16x8*)(xTh + (size_t)(pi * 16 + lr) * 1024 + ks * 32 + kb * 8);

    // stage B, C into LDS (padded rows)
    const f16* src = xbc16 + ((size_t)(b * 1024 + c * 64)) * CONVDIM + 1024;
#pragma unroll
    for (int it = 0; it < 4; ++it) {
        int cid = it * 256 + tid;
        int row = cid >> 4, off = (cid & 15) * 8;
        f16x8 v = *(const f16x8*)(src + (size_t)row * CONVDIM + off);
        if (off < 64) *(f16x8*)&Bs[row][off] = v;
        else          *(f16x8*)&Cs[row][off - 64] = v;
    }

    // per-lane (lane = t): log-decay cumsum + dt
    float2 ad = *(const float2*)&dadt[((size_t)(b * 1024 + c * 64 + lane) * 16 + h) * 2];
    float La = ad.x;
#pragma unroll
    for (int o = 1; o < 64; o <<= 1) {
        float v = __shfl_up(La, o);
        if (lane >= o) La += v;
    }
    float dt_own = ad.y;
    float La63 = __shfl(La, 63);
    float w_own = __expf(La63 - La) * dt_own;   // state weight, <= dt
    LaW[wid][lane] = La;
    dtW[wid][lane] = dt_own;
    __syncthreads();

    // G = C.B^T : each wave one 32x32 quadrant -> GT[s][t]
    {
        int tq = wid & 1, sq = wid >> 1;
        f32x4 g[2][2];
#pragma unroll
        for (int i = 0; i < 2; ++i)
#pragma unroll
            for (int j = 0; j < 2; ++j) g[i][j] = (f32x4){0.f, 0.f, 0.f, 0.f};
#pragma unroll
        for (int ks = 0; ks < 2; ++ks) {
            f16x8 a[2], bb[2];
#pragma unroll
            for (int ti = 0; ti < 2; ++ti)
                a[ti] = *(const f16x8*)&Cs[tq * 32 + ti * 16 + lr][ks * 32 + kb * 8];
#pragma unroll
            for (int si = 0; si < 2; ++si)
                bb[si] = *(const f16x8*)&Bs[sq * 32 + si * 16 + lr][ks * 32 + kb * 8];
#pragma unroll
            for (int ti = 0; ti < 2; ++ti)
#pragma unroll
                for (int si = 0; si < 2; ++si)
                    g[ti][si] = __builtin_amdgcn_mfma_f32_16x16x32_f16(
                        a[ti], bb[si], g[ti][si], 0, 0, 0);
        }
#pragma unroll
        for (int ti = 0; ti < 2; ++ti)
#pragma unroll
            for (int si = 0; si < 2; ++si)
#pragma unroll
                for (int r = 0; r < 4; ++r)
                    GT[sq * 32 + si * 16 + lr][tq * 32 + ti * 16 + kb * 4 + r] = g[ti][si][r];
    }
    __syncthreads();

    // ---- head phase (wave-local) ----
    // sBT[n][t] = B[t][n] * w_t  into Mw[wid]
    {
        f16x8 brow[8];
#pragma unroll
        for (int i = 0; i < 8; ++i) brow[i] = *(const f16x8*)&Bs[lane][i * 8];
#pragma unroll
        for (int i = 0; i < 8; ++i)
#pragma unroll
            for (int j = 0; j < 8; ++j)
                Mw[wid][i * 8 + j][lane] = (f16)((float)brow[i][j] * w_own);
    }
    __builtin_amdgcn_wave_barrier();

    f16x8 sbfrag[4][2];
#pragma unroll
    for (int ni = 0; ni < 4; ++ni)
#pragma unroll
        for (int ks = 0; ks < 2; ++ks)
            sbfrag[ni][ks] = *(const f16x8*)&Mw[wid][ni * 16 + lr][ks * 32 + kb * 8];

    // S[p][n] = sum_t X^T[p][t] sBT[n][t]
    {
        f32x4 accS[4][4];
#pragma unroll
        for (int pi = 0; pi < 4; ++pi)
#pragma unroll
            for (int ni = 0; ni < 4; ++ni) accS[pi][ni] = (f32x4){0.f, 0.f, 0.f, 0.f};
#pragma unroll
        for (int ks = 0; ks < 2; ++ks)
#pragma unroll
            for (int pi = 0; pi < 4; ++pi)
#pragma unroll
                for (int ni = 0; ni < 4; ++ni)
                    accS[pi][ni] = __builtin_amdgcn_mfma_f32_16x16x32_f16(
                        xfrag[pi][ks], sbfrag[ni][ks], accS[pi][ni], 0, 0, 0);
        size_t sbase = ((size_t)((b * 16 + h) * 16 + c)) << 12;
#pragma unroll
        for (int pi = 0; pi < 4; ++pi)
#pragma unroll
            for (int ni = 0; ni < 4; ++ni)
#pragma unroll
                for (int r = 0; r < 4; ++r)
                    Sbuf[sbase + (size_t)(pi * 16 + kb * 4 + r) * 64 + ni * 16 + lr] = accS[pi][ni][r];
        if (lane == 0) Abuf[(b * 16 + h) * 16 + c] = __expf(La63);
    }
    __builtin_amdgcn_wave_barrier();

    // M[t][s] = (s<=t) ? G[t][s]*exp(La_t-La_s)*dt_s : 0   (lane = t)
    {
        int t = lane;
        float la_t = La;
#pragma unroll 4
        for (int s = 0; s < 64; ++s) {
            float g = GT[s][t];
            float las = LaW[wid][s];
            float dts = dtW[wid][s];
            float m = (s <= t) ? g * __expf(la_t - las) * dts : 0.f;
            Mw[wid][t][s] = (f16)m;
        }
    }
    __builtin_amdgcn_wave_barrier();

    // Y_intra[t][p] = sum_s M[t][s] X[s][p]
    {
        f32x4 accY[4][4];
#pragma unroll
        for (int ti = 0; ti < 4; ++ti)
#pragma unroll
            for (int pi = 0; pi < 4; ++pi) accY[ti][pi] = (f32x4){0.f, 0.f, 0.f, 0.f};
#pragma unroll
        for (int ks = 0; ks < 2; ++ks) {
            f16x8 af[4];
#pragma unroll
            for (int ti = 0; ti < 4; ++ti)
                af[ti] = *(const f16x8*)&Mw[wid][ti * 16 + lr][ks * 32 + kb * 8];
#pragma unroll
            for (int ti = 0; ti < 4; ++ti)
#pragma unroll
                for (int pi = 0; pi < 4; ++pi)
                    accY[ti][pi] = __builtin_amdgcn_mfma_f32_16x16x32_f16(
                        af[ti], xfrag[pi][ks], accY[ti][pi], 0, 0, 0);
        }
        float* yp = yss + ((size_t)(b * 1024 + c * 64)) * 1024 + h * 64;
#pragma unroll
        for (int ti = 0; ti < 4; ++ti)
#pragma unroll
            for (int pi = 0; pi < 4; ++pi)
#pragma unroll
                for (int r = 0; r < 4; ++r)
                    yp[(size_t)(ti * 16 + kb * 4 + r) * 1024 + pi * 16 + lr] = accY[ti][pi][r];
    }
}

// ---------------- inter-chunk state recurrence ----------------
__global__ __launch_bounds__(256) void k_hscan(const float* __restrict__ Sbuf,
                                               const float* __restrict__ Abuf,
                                               f16* __restrict__ H16) {
    int tid = threadIdx.x;
    int bh = blockIdx.x;                 // b*16 + h
    size_t base = (size_t)bh << 16;      // 16 chunks * 4096
    int off = tid * 16;
    float Hl[16];
#pragma unroll
    for (int j = 0; j < 16; ++j) Hl[j] = 0.f;
    for (int c = 0; c < NCHUNK; ++c) {
        f16x8 o0, o1;
#pragma unroll
        for (int j = 0; j < 8; ++j) { o0[j] = (f16)Hl[j]; o1[j] = (f16)Hl[j + 8]; }
        *(f16x8*)&H16[base + (size_t)c * 4096 + off] = o0;
        *(f16x8*)&H16[base + (size_t)c * 4096 + off + 8] = o1;
        float A = Abuf[bh * 16 + c];
        const float* sp = &Sbuf[base + (size_t)c * 4096 + off];
        float4 s0 = *(const float4*)(sp);
        float4 s1 = *(const float4*)(sp + 4);
        float4 s2 = *(const float4*)(sp + 8);
        float4 s3 = *(const float4*)(sp + 12);
        float ss[16] = {s0.x, s0.y, s0.z, s0.w, s1.x, s1.y, s1.z, s1.w,
                        s2.x, s2.y, s2.z, s2.w, s3.x, s3.y, s3.z, s3.w};
#pragma unroll
        for (int j = 0; j < 16; ++j) Hl[j] = fmaf(Hl[j], A, ss[j]);
    }
}

// ---------------- SSD part 2: yss += exp(La_t) * (C . Hinit^T) ----------------
__global__ __launch_bounds__(64) void k_ssd2(const f16* __restrict__ xbc16,
                                             const float* __restrict__ dadt,
                                             const f16* __restrict__ H16,
                                             float* __restrict__ yss) {
    __shared__ f16 Csl[64][72];
    __shared__ float La64[64];
    int lane = threadIdx.x;
    int bid = blockIdx.x;               // b*256 + c*16 + h
    int h = bid & 15, c = (bid >> 4) & 15, b = bid >> 8;
    int lr = lane & 15, kb = lane >> 4;

    // H fragments (B-op: col=p, k=n)
    f16x8 hfrag[4][2];
    const f16* Hh = H16 + (((size_t)((b * 16 + h) * 16 + c)) << 12);
#pragma unroll
    for (int pi = 0; pi < 4; ++pi)
#pragma unroll
        for (int ks = 0; ks < 2; ++ks)
            hfrag[pi][ks] = *(const f16x8*)(Hh + (size_t)(pi * 16 + lr) * 64 + ks * 32 + kb * 8);

    // stage C rows
    const f16* csrc = xbc16 + ((size_t)(b * 1024 + c * 64 + lane)) * CONVDIM + 1024 + 64;
#pragma unroll
    for (int i = 0; i < 8; ++i)
        *(f16x8*)&Csl[lane][i * 8] = *(const f16x8*)(csrc + i * 8);

    float2 ad = *(const float2*)&dadt[((size_t)(b * 1024 + c * 64 + lane) * 16 + h) * 2];
    float La = ad.x;
#pragma unroll
    for (int o = 1; o < 64; o <<= 1) {
        float v = __shfl_up(La, o);
        if (lane >= o) La += v;
    }
    La64[lane] = La;
    __syncthreads();

    f32x4 acc[4][4];
#pragma unroll
    for (int ti = 0; ti < 4; ++ti)
#pragma unroll
        for (int pi = 0; pi < 4; ++pi) acc[ti][pi] = (f32x4){0.f, 0.f, 0.f, 0.f};
#pragma unroll
    for (int ks = 0; ks < 2; ++ks) {
        f16x8 af[4];
#pragma unroll
        for (int ti = 0; ti < 4; ++ti)
            af[ti] = *(const f16x8*)&Csl[ti * 16 + lr][ks * 32 + kb * 8];
#pragma unroll
        for (int ti = 0; ti < 4; ++ti)
#pragma unroll
            for (int pi = 0; pi < 4; ++pi)
                acc[ti][pi] = __builtin_amdgcn_mfma_f32_16x16x32_f16(
                    af[ti], hfrag[pi][ks], acc[ti][pi], 0, 0, 0);
    }
    float* yp = yss + ((size_t)(b * 1024 + c * 64)) * 1024 + h * 64;
#pragma unroll
    for (int ti = 0; ti < 4; ++ti)
#pragma unroll
        for (int r = 0; r < 4; ++r) {
            int t = ti * 16 + kb * 4 + r;
            float sc = __expf(La64[t]);
#pragma unroll
            for (int pi = 0; pi < 4; ++pi) {
                size_t idx = (size_t)t * 1024 + pi * 16 + lr;
                yp[idx] += sc * acc[ti][pi][r];
            }
        }
}

// ------ y = (yss + D*xh) * silu(z); RMSNorm * rms_w; write f16 for out_proj ----
__global__ __launch_bounds__(256) void k_gate(const float* __restrict__ zx,
                                              const f16* __restrict__ xbc16,
                                              const float* __restrict__ ssmD,
                                              const float* __restrict__ rmsw,
                                              const float* __restrict__ y,
                                              f16* __restrict__ ygate) {
    __shared__ float sh[4];
    int bl = blockIdx.x, tid = threadIdx.x;
    int c = tid * 4;
    float4 ys = *reinterpret_cast<const float4*>(&y[(size_t)bl * DINNER + c]);
    f16x4 xh4 = *reinterpret_cast<const f16x4*>(&xbc16[(size_t)bl * CONVDIM + c]);
    float4 z4 = *reinterpret_cast<const float4*>(&zx[(size_t)bl * DINPROJ + c]);
    float Dv = ssmD[tid >> 4];
    float v[4] = {ys.x, ys.y, ys.z, ys.w};
    float xv[4] = {(float)xh4.x, (float)xh4.y, (float)xh4.z, (float)xh4.w};
    float zv[4] = {z4.x, z4.y, z4.z, z4.w};
    float ss = 0.f;
#pragma unroll
    for (int j = 0; j < 4; ++j) {
        v[j] = (v[j] + Dv * xv[j]) * silu_f(zv[j]);
        ss += v[j] * v[j];
    }
    int lane = tid & 63, wid = tid >> 6;
#pragma unroll
    for (int o = 32; o > 0; o >>= 1) ss += __shfl_down(ss, o, 64);
    if (lane == 0) sh[wid] = ss;
    __syncthreads();
    float total = sh[0] + sh[1] + sh[2] + sh[3];
    float r = rsqrtf(total * (1.f / DINNER) + 1e-5f);
    f16x4 o4;
    o4.x = (f16)(v[0] * r * rmsw[c + 0]);
    o4.y = (f16)(v[1] * r * rmsw[c + 1]);
    o4.z = (f16)(v[2] * r * rmsw[c + 2]);
    o4.w = (f16)(v[3] * r * rmsw[c + 3]);
    *reinterpret_cast<f16x4*>(&ygate[(size_t)bl * DINNER + c]) = o4;
}

// ---------------- final LayerNorm + mean pool (atomics) ----------------
__global__ __launch_bounds__(256) void k_lnpool(const float* __restrict__ h,
                                                const float* __restrict__ lnw,
                                                const float* __restrict__ lnb,
                                                float* __restrict__ pooled) {
    __shared__ float sh1[4], sh2[4];
    int bl = blockIdx.x, c = threadIdx.x;
    float v = h[(size_t)bl * DMODEL + c];
    float s1 = v, s2 = v * v;
    int lane = c & 63, wid = c >> 6;
#pragma unroll
    for (int o = 32; o > 0; o >>= 1) {
        s1 += __shfl_down(s1, o, 64);
        s2 += __shfl_down(s2, o, 64);
    }
    if (lane == 0) { sh1[wid] = s1; sh2[wid] = s2; }
    __syncthreads();
    float t1 = sh1[0] + sh1[1] + sh1[2] + sh1[3];
    float t2 = sh2[0] + sh2[1] + sh2[2] + sh2[3];
    float mu = t1 * (1.f / DMODEL);
    float var = t2 * (1.f / DMODEL) - mu * mu;
    float o = (v - mu) * rsqrtf(var + 1e-5f) * lnw[c] + lnb[c];
    atomicAdd(&pooled[(bl >> 10) * DMODEL + c], o * (1.f / LOUT));
}

__global__ void k_zero(float* __restrict__ p, int n) {
    int i = blockIdx.x * 256 + threadIdx.x;
    if (i < n) p[i] = 0.f;
}

// ---------------- regression head ----------------
__global__ __launch_bounds__(128) void k_head(const float* __restrict__ pooled,
                                              const float* __restrict__ w1,
                                              const float* __restrict__ b1,
                                              const float* __restrict__ w2,
                                              const float* __restrict__ b2,
                                              float* __restrict__ out) {
    __shared__ float red[2];
    int b = blockIdx.x, j = threadIdx.x;
    float acc = b1[j];
#pragma unroll 8
    for (int d = 0; d < DMODEL; ++d)
        acc = fmaf(pooled[b * DMODEL + d], w1[j * DMODEL + d], acc);
    float r = gelu_f(acc) * w2[j];
#pragma unroll
    for (int o = 32; o > 0; o >>= 1) r += __shfl_down(r, o, 64);
    int lane = j & 63, wid = j >> 6;
    if (lane == 0) red[wid] = r;
    __syncthreads();
    if (j == 0) out[b] = red[0] + red[1] + b2[0];
}

extern "C" void kernel_launch(void* const* d_in, const int* in_sizes, int n_in,
                              void* d_out, int out_size, void* d_ws, size_t ws_size,
                              hipStream_t stream) {
    const float* x         = (const float*)d_in[0];
    const float* conv1_w   = (const float*)d_in[1];
    const float* conv1_b   = (const float*)d_in[2];
    const float* conv2_w   = (const float*)d_in[3];
    const float* conv2_b   = (const float*)d_in[4];
    const float* in_proj_w = (const float*)d_in[5];
    const float* dw_w      = (const float*)d_in[6];
    const float* dw_b      = (const float*)d_in[7];
    const float* dt_bias   = (const float*)d_in[8];
    const float* A_log     = (const float*)d_in[9];
    const float* ssm_D     = (const float*)d_in[10];
    const float* rms_w     = (const float*)d_in[11];
    const float* out_proj_w= (const float*)d_in[12];
    const float* ln_w      = (const float*)d_in[13];
    const float* ln_b      = (const float*)d_in[14];
    const float* reg1_w    = (const float*)d_in[15];
    const float* reg1_b    = (const float*)d_in[16];
    const float* reg2_w    = (const float*)d_in[17];
    const float* reg2_b    = (const float*)d_in[18];

    float* ws = (float*)d_ws;
    size_t off = 0;
    float* c1buf  = ws + off; off += (size_t)NB * 64 * L1OUT;       // 1,048,576
    float* hbuf   = ws + off; off += (size_t)NB * LOUT * DMODEL;    // 2,097,152
    float* zx     = ws + off; off += (size_t)NB * LOUT * DINPROJ;   // 17,956,864
    float* dadt   = ws + off; off += (size_t)NB * LOUT * NHEADS * 2;// 262,144
    float* yss    = ws + off; off += (size_t)NB * LOUT * DINNER;    // 8,388,608
    float* Sbuf   = ws + off; off += (size_t)NB * NHEADS * NCHUNK * 4096; // 8,388,608
    float* Abuf   = ws + off; off += (size_t)NB * NHEADS * NCHUNK;  // 2,048
    float* pooled = ws + off; off += NB * DMODEL;                   // 2,048

    f16* fbase = (f16*)(ws + off);
    size_t foff = 0;
    f16* hbf0   = fbase + foff; foff += (size_t)NB * LOUT * DMODEL;
    f16* hbf1   = fbase + foff; foff += (size_t)NB * LOUT * DMODEL;
    f16* ygate  = fbase + foff; foff += (size_t)NB * LOUT * DINNER;   // also H16
    f16* xbc16  = fbase + foff; foff += (size_t)NB * LOUT * CONVDIM;
    f16* x16T   = fbase + foff; foff += (size_t)NB * NHEADS * HEADDIM * LOUT;
    f16* w_in_h = fbase + foff; foff += (size_t)NLAYERS * NPADIN * DMODEL;
    f16* w_out_h= fbase + foff; foff += (size_t)NLAYERS * DMODEL * DINNER;
    f16* w_c2_h = fbase + foff; foff += (size_t)DMODEL * 1024;
    f16* H16    = ygate;       // aliased: H16 dead before k_gate writes ygate
    f16* im2h   = (f16*)yss;   // aliased: im2col dead before yss first written

    // weight casts
    k_cast_inproj<<<(NLAYERS * NPADIN * 256) / 256, 256, 0, stream>>>(in_proj_w, w_in_h);
    k_cast<<<(NLAYERS * DMODEL * DINNER) / 256, 256, 0, stream>>>(
        out_proj_w, w_out_h, NLAYERS * DMODEL * DINNER);
    k_cast<<<(DMODEL * 1024) / 256, 256, 0, stream>>>(conv2_w, w_c2_h, DMODEL * 1024);

    // front-end convs
    k_conv1<<<(NB * 64 * L1OUT) / 256, 256, 0, stream>>>(x, conv1_w, conv1_b, c1buf);
    k_im2col<<<(NB * LOUT * 1024) / 256, 256, 0, stream>>>(c1buf, im2h);
    {
        dim3 g(256 / 128, 8192 / 64);
        k_hgemm<64, 1><<<g, 256, 0, stream>>>(im2h, w_c2_h, nullptr, hbf0,
                                              8192, 256, 1024, conv2_b);
    }

    f16* hcur = hbf0;
    f16* hnxt = hbf1;
    for (int i = 0; i < NLAYERS; ++i) {
        {
            dim3 g(NPADIN / 128, 8192 / 128);
            k_hgemm<128, 0><<<g, 256, 0, stream>>>(
                hcur, w_in_h + (size_t)i * NPADIN * DMODEL, zx, nullptr,
                8192, DINPROJ, DMODEL, nullptr);
        }
        k_dwconv<<<(NB * LOUT * CONVDIM) / 256, 256, 0, stream>>>(
            zx, dw_w + (size_t)i * CONVDIM * 4, dw_b + (size_t)i * CONVDIM, xbc16);
        k_dt<<<(NB * LOUT * NHEADS) / 256, 256, 0, stream>>>(
            zx, dt_bias + i * NHEADS, A_log + i * NHEADS, dadt);
        k_xT<<<NB * NHEADS * NCHUNK, 256, 0, stream>>>(xbc16, x16T);
        k_ssd1<<<NB * NCHUNK * 4, 256, 0, stream>>>(xbc16, x16T, dadt, yss, Sbuf, Abuf);
        k_hscan<<<NB * NHEADS, 256, 0, stream>>>(Sbuf, Abuf, H16);
        k_ssd2<<<NB * NCHUNK * NHEADS, 64, 0, stream>>>(xbc16, dadt, H16, yss);
        k_gate<<<NB * LOUT, 256, 0, stream>>>(zx, xbc16, ssm_D + i * NHEADS,
                                              rms_w + (size_t)i * DINNER, yss, ygate);
        {
            dim3 g(DMODEL / 128, 8192 / 64);
            k_hgemm<64, 0><<<g, 256, 0, stream>>>(
                ygate, w_out_h + (size_t)i * DMODEL * DINNER, hbuf, hnxt,
                8192, DMODEL, DINNER, nullptr);
        }
        f16* tmp = hcur; hcur = hnxt; hnxt = tmp;
    }

    // final LN + pool + head
    k_zero<<<(NB * DMODEL + 255) / 256, 256, 0, stream>>>(pooled, NB * DMODEL);
    k_lnpool<<<NB * LOUT, 256, 0, stream>>>(hbuf, ln_w, ln_b, pooled);
    k_head<<<NB, 128, 0, stream>>>(pooled, reg1_w, reg1_b, reg2_w, reg2_b, (float*)d_out);
}

// Round 6
// 1337.459 us; speedup vs baseline: 2.5786x; 1.1857x over previous
//
#include <hip/hip_runtime.h>
#include <math.h>

#define NB       8
#define SEQ      8192
#define L1OUT    2048
#define LOUT     1024
#define DMODEL   256
#define DINNER   1024
#define NHEADS   16
#define HEADDIM  64
#define DSTATE   64
#define CONVDIM  1152
#define DINPROJ  2192
#define NPADIN   2304     // in_proj rows padded to multiple of 128
#define NLAYERS  8
#define NCHUNK   16
#define Q        64       // chunk length
#define CDT      (CONVDIM + 16)   // dwconv grid includes 16 dt channels

typedef _Float16 f16;
typedef __attribute__((ext_vector_type(8))) _Float16 f16x8;
typedef __attribute__((ext_vector_type(4))) _Float16 f16x4;
typedef __attribute__((ext_vector_type(4))) float    f32x4;

__device__ __forceinline__ float gelu_f(float v) {
    return 0.5f * v * (1.0f + erff(v * 0.70710678118654752f));
}
__device__ __forceinline__ float silu_f(float v) {
    return v / (1.0f + expf(-v));
}

__device__ __forceinline__ void gload16(const void* g, void* l) {
    __builtin_amdgcn_global_load_lds(
        (const __attribute__((address_space(1))) unsigned int*)g,
        (__attribute__((address_space(3))) unsigned int*)l, 16, 0, 0);
}

// ---------------- weight casts ----------------
__global__ __launch_bounds__(256) void k_cast(const float* __restrict__ in,
                                              f16* __restrict__ out, int n) {
    int i = blockIdx.x * 256 + threadIdx.x;
    if (i < n) out[i] = (f16)in[i];
}

__global__ __launch_bounds__(256) void k_cast_inproj(const float* __restrict__ w,
                                                     f16* __restrict__ out) {
    int idx = blockIdx.x * 256 + threadIdx.x;       // 8*2304*256
    int c = idx & 255;
    int r = (idx >> 8) % NPADIN;
    int l = idx / (NPADIN * 256);
    float v = (r < DINPROJ) ? w[((size_t)l * DINPROJ + r) * 256 + c] : 0.f;
    out[idx] = (f16)v;
}

// ---------------- conv1 (3->64, k16, s4, pad6) + GELU ----------------
__global__ __launch_bounds__(256) void k_conv1(const float* __restrict__ x,
                                               const float* __restrict__ w,
                                               const float* __restrict__ bias,
                                               float* __restrict__ out) {
    int idx = blockIdx.x * 256 + threadIdx.x;      // NB*64*L1OUT
    int t  = idx & (L1OUT - 1);
    int co = (idx >> 11) & 63;
    int b  = idx >> 17;
    float s = bias[co];
#pragma unroll
    for (int ci = 0; ci < 3; ++ci) {
        const float* xp = x + ((size_t)b * 3 + ci) * SEQ;
        const float* wp = w + (co * 3 + ci) * 16;
#pragma unroll
        for (int k = 0; k < 16; ++k) {
            int pos = t * 4 + k - 6;
            if (pos >= 0 && pos < SEQ) s = fmaf(xp[pos], wp[k], s);
        }
    }
    out[idx] = gelu_f(s);
}

// ---------------- im2col for conv2 (64ch, k16, s2, pad7) -> f16 ----------------
__global__ __launch_bounds__(256) void k_im2col(const float* __restrict__ h1,
                                                f16* __restrict__ A) {
    int idx = blockIdx.x * 256 + threadIdx.x;      // 8192*1024
    int col = idx & 1023;
    int row = idx >> 10;
    int t = row & (LOUT - 1);
    int b = row >> 10;
    int ci = col >> 4, k = col & 15;
    int pos = t * 2 + k - 7;
    float v = 0.f;
    if (pos >= 0 && pos < L1OUT) v = h1[((size_t)b * 64 + ci) * L1OUT + pos];
    A[idx] = (f16)v;
}

// ---------------- fp16 MFMA GEMM: C[M,N] = A[M,K] * B[Npad,K]^T ----------------
// Dtr: optional compact fp32 copy of cols [DINNER+CONVDIM, DINPROJ) (dt raw).
template<int BM, int EPI>
__global__ __launch_bounds__(256) void k_hgemm(const f16* __restrict__ A,
                                               const f16* __restrict__ Bw,
                                               float* __restrict__ Cf,
                                               f16* __restrict__ Ch,
                                               float* __restrict__ Dtr,
                                               int M, int N, int K,
                                               const float* __restrict__ bias) {
    constexpr int MI = BM / 32;
    __shared__ f16 As[BM * 32];
    __shared__ f16 Bs[128 * 32];
    int tid  = threadIdx.x;
    int lane = tid & 63, wid = tid >> 6;
    int wm = wid >> 1, wn = wid & 1;
    int row0 = blockIdx.y * BM, col0 = blockIdx.x * 128;
    int lr = lane & 15, kb = lane >> 4;

    f32x4 acc[MI][4];
#pragma unroll
    for (int mi = 0; mi < MI; ++mi)
#pragma unroll
        for (int ni = 0; ni < 4; ++ni)
            acc[mi][ni] = (f32x4){0.f, 0.f, 0.f, 0.f};

    int srow = tid >> 2;
    int scol = (tid & 3) * 8;

    for (int k0 = 0; k0 < K; k0 += 32) {
        __syncthreads();
#pragma unroll
        for (int is = 0; is < BM / 64; ++is)
            gload16(A + (size_t)(row0 + is * 64 + srow) * K + k0 + scol,
                    &As[is * 2048 + wid * 512]);
#pragma unroll
        for (int is = 0; is < 2; ++is)
            gload16(Bw + (size_t)(col0 + is * 64 + srow) * K + k0 + scol,
                    &Bs[is * 2048 + wid * 512]);
        __syncthreads();

        f16x8 a[MI], b[4];
#pragma unroll
        for (int mi = 0; mi < MI; ++mi)
            a[mi] = *reinterpret_cast<const f16x8*>(
                &As[(wm * (BM / 2) + mi * 16 + lr) * 32 + kb * 8]);
#pragma unroll
        for (int ni = 0; ni < 4; ++ni)
            b[ni] = *reinterpret_cast<const f16x8*>(
                &Bs[(wn * 64 + ni * 16 + lr) * 32 + kb * 8]);
#pragma unroll
        for (int mi = 0; mi < MI; ++mi)
#pragma unroll
            for (int ni = 0; ni < 4; ++ni)
                acc[mi][ni] = __builtin_amdgcn_mfma_f32_16x16x32_f16(
                    a[mi], b[ni], acc[mi][ni], 0, 0, 0);
    }

#pragma unroll
    for (int mi = 0; mi < MI; ++mi)
#pragma unroll
        for (int ni = 0; ni < 4; ++ni) {
            int ccol = col0 + wn * 64 + ni * 16 + lr;
            if (ccol < N) {
                int rbase = row0 + wm * (BM / 2) + mi * 16 + kb * 4;
                f32x4 v = acc[mi][ni];
#pragma unroll
                for (int r = 0; r < 4; ++r) {
                    float val = v[r];
                    if (EPI == 1) val = gelu_f(val + bias[ccol]);
                    if (Cf) Cf[(size_t)(rbase + r) * N + ccol] = val;
                    if (Ch) Ch[(size_t)(rbase + r) * N + ccol] = (f16)val;
                    if (Dtr && ccol >= DINNER + CONVDIM)
                        Dtr[(size_t)(rbase + r) * 16 + (ccol - (DINNER + CONVDIM))] = val;
                }
            }
        }
}

// --- depthwise causal conv (k=4) + SiLU -> f16, fused with dt/dA compute ----
__global__ __launch_bounds__(256) void k_dwconv(const f16* __restrict__ zx16,
                                                const float* __restrict__ dtraw,
                                                const float* __restrict__ w,
                                                const float* __restrict__ bias,
                                                const float* __restrict__ dt_bias,
                                                const float* __restrict__ A_log,
                                                f16* __restrict__ out16,
                                                float* __restrict__ dadt) {
    int idx = blockIdx.x * 256 + threadIdx.x;      // NB*LOUT*CDT
    int c  = idx % CDT;
    int bl = idx / CDT;
    int l  = bl & (LOUT - 1);
    if (c < CONVDIM) {
        const float* wp = w + c * 4;
        float s = bias[c];
#pragma unroll
        for (int k = 0; k < 4; ++k) {
            int t = l - 3 + k;
            if (t >= 0)
                s = fmaf((float)zx16[(size_t)(bl - 3 + k) * DINPROJ + DINNER + c], wp[k], s);
        }
        out16[(size_t)bl * CONVDIM + c] = (f16)silu_f(s);
    } else {
        int hh = c - CONVDIM;
        float raw = dtraw[bl * 16 + hh] + dt_bias[hh];
        float dtv = (raw > 20.f) ? raw : log1pf(expf(raw));
        float lda = -expf(A_log[hh]) * dtv;
        *(float2*)&dadt[(size_t)(bl * 16 + hh) * 2] = make_float2(lda, dtv);
    }
}

// ---------------- SSD part 1: per (b, chunk, 4 heads) ----------------
// stage B/C/X in LDS; G = C.B^T; per head: S = X^T.(w*B)^T (f16 out),
// M = masked decay * G, Y_intra = M.X -> yss (fp32)
__global__ __launch_bounds__(256) void k_ssd1(const f16* __restrict__ xbc16,
                                              const float* __restrict__ dadt,
                                              float* __restrict__ yss,
                                              f16* __restrict__ Sbuf16,
                                              float* __restrict__ Abuf) {
    __shared__ f16 Bs[64][72];
    __shared__ f16 Cs[64][72];
    __shared__ float GT[64][68];            // GT[s][t]
    __shared__ f16 Mw[4][64][72];           // X staging, then per-wave sBT / M
    __shared__ float2 LaDt[4][64];

    int tid = threadIdx.x, lane = tid & 63, wid = tid >> 6;
    int bid = blockIdx.x;
    int hq = bid & 3, c = (bid >> 2) & 15, b = bid >> 6;
    int h = hq * 4 + wid;
    int lr = lane & 15, kb = lane >> 4;

    // stage B, C into LDS (padded rows)
    const f16* src = xbc16 + ((size_t)(b * 1024 + c * 64)) * CONVDIM + 1024;
#pragma unroll
    for (int it = 0; it < 4; ++it) {
        int cid = it * 256 + tid;
        int row = cid >> 4, off = (cid & 15) * 8;
        f16x8 v = *(const f16x8*)(src + (size_t)row * CONVDIM + off);
        if (off < 64) *(f16x8*)&Bs[row][off] = v;
        else          *(f16x8*)&Cs[row][off - 64] = v;
    }

    // stage X rows (4 heads worth) into Mw region: Xs[t][ch], pad 260
    f16* Xs = &Mw[0][0][0];
    const f16* xsrc = xbc16 + ((size_t)(b * 1024 + c * 64)) * CONVDIM + hq * 256;
#pragma unroll
    for (int it = 0; it < 8; ++it) {
        int cid = it * 256 + tid;
        int row = cid >> 5, chk = cid & 31;
        f16x4 v0 = *(const f16x4*)(xsrc + (size_t)row * CONVDIM + chk * 8);
        f16x4 v1 = *(const f16x4*)(xsrc + (size_t)row * CONVDIM + chk * 8 + 4);
        *(f16x4*)&Xs[row * 260 + chk * 8] = v0;
        *(f16x4*)&Xs[row * 260 + chk * 8 + 4] = v1;
    }

    // per-lane (lane = t): log-decay cumsum + dt
    float2 ad = *(const float2*)&dadt[((size_t)(b * 1024 + c * 64 + lane) * 16 + h) * 2];
    float La = ad.x;
#pragma unroll
    for (int o = 1; o < 64; o <<= 1) {
        float v = __shfl_up(La, o);
        if (lane >= o) La += v;
    }
    float dt_own = ad.y;
    float La63 = __shfl(La, 63);
    float w_own = __expf(La63 - La) * dt_own;   // state weight, <= dt
    LaDt[wid][lane] = make_float2(La, dt_own);
    __syncthreads();

    // read X^T fragments from LDS (row p, k=t)
    f16x8 xfrag[4][2];
#pragma unroll
    for (int pi = 0; pi < 4; ++pi)
#pragma unroll
        for (int ks = 0; ks < 2; ++ks) {
            f16x8 v;
#pragma unroll
            for (int j = 0; j < 8; ++j)
                v[j] = Xs[(ks * 32 + kb * 8 + j) * 260 + wid * 64 + pi * 16 + lr];
            xfrag[pi][ks] = v;
        }

    // G = C.B^T : each wave one 32x32 quadrant -> GT[s][t]
    {
        int tq = wid & 1, sq = wid >> 1;
        f32x4 g[2][2];
#pragma unroll
        for (int i = 0; i < 2; ++i)
#pragma unroll
            for (int j = 0; j < 2; ++j) g[i][j] = (f32x4){0.f, 0.f, 0.f, 0.f};
#pragma unroll
        for (int ks = 0; ks < 2; ++ks) {
            f16x8 a[2], bb[2];
#pragma unroll
            for (int ti = 0; ti < 2; ++ti)
                a[ti] = *(const f16x8*)&Cs[tq * 32 + ti * 16 + lr][ks * 32 + kb * 8];
#pragma unroll
            for (int si = 0; si < 2; ++si)
                bb[si] = *(const f16x8*)&Bs[sq * 32 + si * 16 + lr][ks * 32 + kb * 8];
#pragma unroll
            for (int ti = 0; ti < 2; ++ti)
#pragma unroll
                for (int si = 0; si < 2; ++si)
                    g[ti][si] = __builtin_amdgcn_mfma_f32_16x16x32_f16(
                        a[ti], bb[si], g[ti][si], 0, 0, 0);
        }
#pragma unroll
        for (int ti = 0; ti < 2; ++ti)
#pragma unroll
            for (int si = 0; si < 2; ++si)
#pragma unroll
                for (int r = 0; r < 4; ++r)
                    GT[sq * 32 + si * 16 + lr][tq * 32 + ti * 16 + kb * 4 + r] = g[ti][si][r];
    }
    __syncthreads();   // GT ready; all xfrag reads done -> Mw reusable

    // ---- head phase (wave-local) ----
    // sBT[n][t] = B[t][n] * w_t  into Mw[wid]
    {
        f16x8 brow[8];
#pragma unroll
        for (int i = 0; i < 8; ++i) brow[i] = *(const f16x8*)&Bs[lane][i * 8];
#pragma unroll
        for (int i = 0; i < 8; ++i)
#pragma unroll
            for (int j = 0; j < 8; ++j)
                Mw[wid][i * 8 + j][lane] = (f16)((float)brow[i][j] * w_own);
    }
    __builtin_amdgcn_wave_barrier();

    f16x8 sbfrag[4][2];
#pragma unroll
    for (int ni = 0; ni < 4; ++ni)
#pragma unroll
        for (int ks = 0; ks < 2; ++ks)
            sbfrag[ni][ks] = *(const f16x8*)&Mw[wid][ni * 16 + lr][ks * 32 + kb * 8];

    // S[p][n] = sum_t X^T[p][t] sBT[n][t]  -> f16
    {
        f32x4 accS[4][4];
#pragma unroll
        for (int pi = 0; pi < 4; ++pi)
#pragma unroll
            for (int ni = 0; ni < 4; ++ni) accS[pi][ni] = (f32x4){0.f, 0.f, 0.f, 0.f};
#pragma unroll
        for (int ks = 0; ks < 2; ++ks)
#pragma unroll
            for (int pi = 0; pi < 4; ++pi)
#pragma unroll
                for (int ni = 0; ni < 4; ++ni)
                    accS[pi][ni] = __builtin_amdgcn_mfma_f32_16x16x32_f16(
                        xfrag[pi][ks], sbfrag[ni][ks], accS[pi][ni], 0, 0, 0);
        size_t sbase = ((size_t)((b * 16 + h) * 16 + c)) << 12;
#pragma unroll
        for (int pi = 0; pi < 4; ++pi)
#pragma unroll
            for (int ni = 0; ni < 4; ++ni)
#pragma unroll
                for (int r = 0; r < 4; ++r)
                    Sbuf16[sbase + (size_t)(pi * 16 + kb * 4 + r) * 64 + ni * 16 + lr] =
                        (f16)accS[pi][ni][r];
        if (lane == 0) Abuf[(b * 16 + h) * 16 + c] = __expf(La63);
    }
    __builtin_amdgcn_wave_barrier();

    // M[t][s] = (s<=t) ? G[t][s]*exp(La_t-La_s)*dt_s : 0   (lane = t)
    {
        int t = lane;
        float la_t = La;
#pragma unroll
        for (int s8 = 0; s8 < 8; ++s8) {
            f16x8 mv;
#pragma unroll
            for (int j = 0; j < 8; ++j) {
                int s = s8 * 8 + j;
                float2 ld = LaDt[wid][s];
                float m = (s <= t) ? GT[s][t] * __expf(la_t - ld.x) * ld.y : 0.f;
                mv[j] = (f16)m;
            }
            *(f16x8*)&Mw[wid][t][s8 * 8] = mv;
        }
    }
    __builtin_amdgcn_wave_barrier();

    // Y_intra[t][p] = sum_s M[t][s] X[s][p]
    {
        f32x4 accY[4][4];
#pragma unroll
        for (int ti = 0; ti < 4; ++ti)
#pragma unroll
            for (int pi = 0; pi < 4; ++pi) accY[ti][pi] = (f32x4){0.f, 0.f, 0.f, 0.f};
#pragma unroll
        for (int ks = 0; ks < 2; ++ks) {
            f16x8 af[4];
#pragma unroll
            for (int ti = 0; ti < 4; ++ti)
                af[ti] = *(const f16x8*)&Mw[wid][ti * 16 + lr][ks * 32 + kb * 8];
#pragma unroll
            for (int ti = 0; ti < 4; ++ti)
#pragma unroll
                for (int pi = 0; pi < 4; ++pi)
                    accY[ti][pi] = __builtin_amdgcn_mfma_f32_16x16x32_f16(
                        af[ti], xfrag[pi][ks], accY[ti][pi], 0, 0, 0);
        }
        float* yp = yss + ((size_t)(b * 1024 + c * 64)) * 1024 + h * 64;
#pragma unroll
        for (int ti = 0; ti < 4; ++ti)
#pragma unroll
            for (int pi = 0; pi < 4; ++pi)
#pragma unroll
                for (int r = 0; r < 4; ++r)
                    yp[(size_t)(ti * 16 + kb * 4 + r) * 1024 + pi * 16 + lr] = accY[ti][pi][r];
    }
}

// ---------------- inter-chunk state recurrence (f16 S in, f16 H out) --------
__global__ __launch_bounds__(64) void k_hscan(const f16* __restrict__ Sbuf16,
                                              const float* __restrict__ Abuf,
                                              f16* __restrict__ H16) {
    int tid = threadIdx.x;
    int bid = blockIdx.x;                // 512: bh*4 + q
    int bh = bid >> 2, q = bid & 3;
    size_t base = (size_t)bh << 16;      // 16 chunks * 4096
    int off = q * 1024 + tid * 16;
    float Hl[16];
#pragma unroll
    for (int j = 0; j < 16; ++j) Hl[j] = 0.f;
    for (int c = 0; c < NCHUNK; ++c) {
        f16x8 o0, o1;
#pragma unroll
        for (int j = 0; j < 8; ++j) { o0[j] = (f16)Hl[j]; o1[j] = (f16)Hl[j + 8]; }
        *(f16x8*)&H16[base + (size_t)c * 4096 + off] = o0;
        *(f16x8*)&H16[base + (size_t)c * 4096 + off + 8] = o1;
        float A = Abuf[bh * 16 + c];
        f16x8 s0 = *(const f16x8*)&Sbuf16[base + (size_t)c * 4096 + off];
        f16x8 s1 = *(const f16x8*)&Sbuf16[base + (size_t)c * 4096 + off + 8];
#pragma unroll
        for (int j = 0; j < 8; ++j) {
            Hl[j]     = fmaf(Hl[j],     A, (float)s0[j]);
            Hl[j + 8] = fmaf(Hl[j + 8], A, (float)s1[j]);
        }
    }
}

// ------------- SSD part 2: y2 = exp(La_t) * (C . Hinit^T)  (f16 out) --------
__global__ __launch_bounds__(64) void k_ssd2(const f16* __restrict__ xbc16,
                                             const float* __restrict__ dadt,
                                             const f16* __restrict__ H16,
                                             f16* __restrict__ y2) {
    __shared__ f16 Csl[64][72];
    __shared__ float La64[64];
    int lane = threadIdx.x;
    int bid = blockIdx.x;               // b*256 + c*16 + h
    int h = bid & 15, c = (bid >> 4) & 15, b = bid >> 8;
    int lr = lane & 15, kb = lane >> 4;

    f16x8 hfrag[4][2];
    const f16* Hh = H16 + (((size_t)((b * 16 + h) * 16 + c)) << 12);
#pragma unroll
    for (int pi = 0; pi < 4; ++pi)
#pragma unroll
        for (int ks = 0; ks < 2; ++ks)
            hfrag[pi][ks] = *(const f16x8*)(Hh + (size_t)(pi * 16 + lr) * 64 + ks * 32 + kb * 8);

    const f16* csrc = xbc16 + ((size_t)(b * 1024 + c * 64 + lane)) * CONVDIM + 1024 + 64;
#pragma unroll
    for (int i = 0; i < 8; ++i)
        *(f16x8*)&Csl[lane][i * 8] = *(const f16x8*)(csrc + i * 8);

    float2 ad = *(const float2*)&dadt[((size_t)(b * 1024 + c * 64 + lane) * 16 + h) * 2];
    float La = ad.x;
#pragma unroll
    for (int o = 1; o < 64; o <<= 1) {
        float v = __shfl_up(La, o);
        if (lane >= o) La += v;
    }
    La64[lane] = La;
    __syncthreads();

    f32x4 acc[4][4];
#pragma unroll
    for (int ti = 0; ti < 4; ++ti)
#pragma unroll
        for (int pi = 0; pi < 4; ++pi) acc[ti][pi] = (f32x4){0.f, 0.f, 0.f, 0.f};
#pragma unroll
    for (int ks = 0; ks < 2; ++ks) {
        f16x8 af[4];
#pragma unroll
        for (int ti = 0; ti < 4; ++ti)
            af[ti] = *(const f16x8*)&Csl[ti * 16 + lr][ks * 32 + kb * 8];
#pragma unroll
        for (int ti = 0; ti < 4; ++ti)
#pragma unroll
            for (int pi = 0; pi < 4; ++pi)
                acc[ti][pi] = __builtin_amdgcn_mfma_f32_16x16x32_f16(
                    af[ti], hfrag[pi][ks], acc[ti][pi], 0, 0, 0);
    }
    f16* yp = y2 + ((size_t)(b * 1024 + c * 64)) * 1024 + h * 64;
#pragma unroll
    for (int ti = 0; ti < 4; ++ti)
#pragma unroll
        for (int r = 0; r < 4; ++r) {
            int t = ti * 16 + kb * 4 + r;
            float sc = __expf(La64[t]);
#pragma unroll
            for (int pi = 0; pi < 4; ++pi)
                yp[(size_t)t * 1024 + pi * 16 + lr] = (f16)(sc * acc[ti][pi][r]);
        }
}

// -- y = (yss + y2 + D*xh) * silu(z); RMSNorm * rms_w; f16 out for out_proj --
__global__ __launch_bounds__(256) void k_gate(const f16* __restrict__ zx16,
                                              const f16* __restrict__ xbc16,
                                              const float* __restrict__ ssmD,
                                              const float* __restrict__ rmsw,
                                              const float* __restrict__ y,
                                              const f16* __restrict__ y2,
                                              f16* __restrict__ ygate) {
    __shared__ float sh[4];
    int bl = blockIdx.x, tid = threadIdx.x;
    int c = tid * 4;
    float4 ys = *reinterpret_cast<const float4*>(&y[(size_t)bl * DINNER + c]);
    f16x4 y2v = *reinterpret_cast<const f16x4*>(&y2[(size_t)bl * DINNER + c]);
    f16x4 xh4 = *reinterpret_cast<const f16x4*>(&xbc16[(size_t)bl * CONVDIM + c]);
    f16x4 z4  = *reinterpret_cast<const f16x4*>(&zx16[(size_t)bl * DINPROJ + c]);
    float Dv = ssmD[tid >> 4];
    float v[4] = {ys.x, ys.y, ys.z, ys.w};
    float ss = 0.f;
#pragma unroll
    for (int j = 0; j < 4; ++j) {
        v[j] = (v[j] + (float)y2v[j] + Dv * (float)xh4[j]) * silu_f((float)z4[j]);
        ss += v[j] * v[j];
    }
    int lane = tid & 63, wid = tid >> 6;
#pragma unroll
    for (int o = 32; o > 0; o >>= 1) ss += __shfl_down(ss, o, 64);
    if (lane == 0) sh[wid] = ss;
    __syncthreads();
    float total = sh[0] + sh[1] + sh[2] + sh[3];
    float r = rsqrtf(total * (1.f / DINNER) + 1e-5f);
    f16x4 o4;
    o4.x = (f16)(v[0] * r * rmsw[c + 0]);
    o4.y = (f16)(v[1] * r * rmsw[c + 1]);
    o4.z = (f16)(v[2] * r * rmsw[c + 2]);
    o4.w = (f16)(v[3] * r * rmsw[c + 3]);
    *reinterpret_cast<f16x4*>(&ygate[(size_t)bl * DINNER + c]) = o4;
}

// ------- final LayerNorm + mean pool: wave-per-row, block partial, 1 atomic --
__global__ __launch_bounds__(256) void k_lnpool(const float* __restrict__ h,
                                                const float* __restrict__ lnw,
                                                const float* __restrict__ lnb,
                                                float* __restrict__ pooled) {
    __shared__ float pl[4][256];
    int bid = blockIdx.x;                // 8 * 32
    int b = bid >> 5, seg = bid & 31;
    int tid = threadIdx.x, lane = tid & 63, w = tid >> 6;
    int c4 = lane * 4;
    float4 lw = *(const float4*)&lnw[c4];
    float4 lb = *(const float4*)&lnb[c4];
    float acc0 = 0.f, acc1 = 0.f, acc2 = 0.f, acc3 = 0.f;
    const float* hb = h + ((size_t)b * 1024 + seg * 32 + w * 8) * DMODEL;
#pragma unroll
    for (int i = 0; i < 8; ++i) {
        float4 v = *(const float4*)(hb + (size_t)i * DMODEL + c4);
        float s1 = v.x + v.y + v.z + v.w;
        float s2 = v.x * v.x + v.y * v.y + v.z * v.z + v.w * v.w;
#pragma unroll
        for (int o = 32; o > 0; o >>= 1) {
            s1 += __shfl_xor(s1, o);
            s2 += __shfl_xor(s2, o);
        }
        float mu = s1 * (1.f / DMODEL);
        float var = s2 * (1.f / DMODEL) - mu * mu;
        float rr = rsqrtf(var + 1e-5f);
        acc0 += (v.x - mu) * rr * lw.x + lb.x;
        acc1 += (v.y - mu) * rr * lw.y + lb.y;
        acc2 += (v.z - mu) * rr * lw.z + lb.z;
        acc3 += (v.w - mu) * rr * lw.w + lb.w;
    }
    pl[w][c4 + 0] = acc0; pl[w][c4 + 1] = acc1;
    pl[w][c4 + 2] = acc2; pl[w][c4 + 3] = acc3;
    __syncthreads();
    float tot = pl[0][tid] + pl[1][tid] + pl[2][tid] + pl[3][tid];
    atomicAdd(&pooled[b * DMODEL + tid], tot * (1.f / LOUT));
}

__global__ void k_zero(float* __restrict__ p, int n) {
    int i = blockIdx.x * 256 + threadIdx.x;
    if (i < n) p[i] = 0.f;
}

// ---------------- regression head ----------------
__global__ __launch_bounds__(128) void k_head(const float* __restrict__ pooled,
                                              const float* __restrict__ w1,
                                              const float* __restrict__ b1,
                                              const float* __restrict__ w2,
                                              const float* __restrict__ b2,
                                              float* __restrict__ out) {
    __shared__ float red[2];
    int b = blockIdx.x, j = threadIdx.x;
    float acc = b1[j];
#pragma unroll 8
    for (int d = 0; d < DMODEL; ++d)
        acc = fmaf(pooled[b * DMODEL + d], w1[j * DMODEL + d], acc);
    float r = gelu_f(acc) * w2[j];
#pragma unroll
    for (int o = 32; o > 0; o >>= 1) r += __shfl_down(r, o, 64);
    int lane = j & 63, wid = j >> 6;
    if (lane == 0) red[wid] = r;
    __syncthreads();
    if (j == 0) out[b] = red[0] + red[1] + b2[0];
}

extern "C" void kernel_launch(void* const* d_in, const int* in_sizes, int n_in,
                              void* d_out, int out_size, void* d_ws, size_t ws_size,
                              hipStream_t stream) {
    const float* x         = (const float*)d_in[0];
    const float* conv1_w   = (const float*)d_in[1];
    const float* conv1_b   = (const float*)d_in[2];
    const float* conv2_w   = (const float*)d_in[3];
    const float* conv2_b   = (const float*)d_in[4];
    const float* in_proj_w = (const float*)d_in[5];
    const float* dw_w      = (const float*)d_in[6];
    const float* dw_b      = (const float*)d_in[7];
    const float* dt_bias   = (const float*)d_in[8];
    const float* A_log     = (const float*)d_in[9];
    const float* ssm_D     = (const float*)d_in[10];
    const float* rms_w     = (const float*)d_in[11];
    const float* out_proj_w= (const float*)d_in[12];
    const float* ln_w      = (const float*)d_in[13];
    const float* ln_b      = (const float*)d_in[14];
    const float* reg1_w    = (const float*)d_in[15];
    const float* reg1_b    = (const float*)d_in[16];
    const float* reg2_w    = (const float*)d_in[17];
    const float* reg2_b    = (const float*)d_in[18];

    float* ws = (float*)d_ws;
    size_t off = 0;
    float* c1buf  = ws + off; off += (size_t)NB * 64 * L1OUT;       // 1,048,576
    float* hbuf   = ws + off; off += (size_t)NB * LOUT * DMODEL;    // 2,097,152
    float* dtraw  = ws + off; off += (size_t)NB * LOUT * 16;        // 131,072
    float* dadt   = ws + off; off += (size_t)NB * LOUT * NHEADS * 2;// 262,144
    float* yss    = ws + off; off += (size_t)NB * LOUT * DINNER;    // 8,388,608
    float* Abuf   = ws + off; off += (size_t)NB * NHEADS * NCHUNK;  // 2,048
    float* pooled = ws + off; off += NB * DMODEL;                   // 2,048

    f16* fbase = (f16*)(ws + off);
    size_t foff = 0;
    f16* hbf0   = fbase + foff; foff += (size_t)NB * LOUT * DMODEL;
    f16* hbf1   = fbase + foff; foff += (size_t)NB * LOUT * DMODEL;
    f16* ygate  = fbase + foff; foff += (size_t)NB * LOUT * DINNER;   // also H16
    f16* y2     = fbase + foff; foff += (size_t)NB * LOUT * DINNER;
    f16* xbc16  = fbase + foff; foff += (size_t)NB * LOUT * CONVDIM;
    f16* zx16   = fbase + foff; foff += (size_t)NB * LOUT * DINPROJ;
    f16* Sbuf16 = fbase + foff; foff += (size_t)NB * NHEADS * NCHUNK * 4096;
    f16* w_in_h = fbase + foff; foff += (size_t)NLAYERS * NPADIN * DMODEL;
    f16* w_out_h= fbase + foff; foff += (size_t)NLAYERS * DMODEL * DINNER;
    f16* w_c2_h = fbase + foff; foff += (size_t)DMODEL * 1024;
    f16* H16    = ygate;       // aliased: H16 dead before k_gate writes ygate
    f16* im2h   = (f16*)yss;   // aliased: im2col dead before yss first written

    // weight casts
    k_cast_inproj<<<(NLAYERS * NPADIN * 256) / 256, 256, 0, stream>>>(in_proj_w, w_in_h);
    k_cast<<<(NLAYERS * DMODEL * DINNER) / 256, 256, 0, stream>>>(
        out_proj_w, w_out_h, NLAYERS * DMODEL * DINNER);
    k_cast<<<(DMODEL * 1024) / 256, 256, 0, stream>>>(conv2_w, w_c2_h, DMODEL * 1024);

    // front-end convs
    k_conv1<<<(NB * 64 * L1OUT) / 256, 256, 0, stream>>>(x, conv1_w, conv1_b, c1buf);
    k_im2col<<<(NB * LOUT * 1024) / 256, 256, 0, stream>>>(c1buf, im2h);
    {
        dim3 g(256 / 128, 8192 / 64);
        k_hgemm<64, 1><<<g, 256, 0, stream>>>(im2h, w_c2_h, nullptr, hbf0, nullptr,
                                              8192, 256, 1024, conv2_b);
    }

    f16* hcur = hbf0;
    f16* hnxt = hbf1;
    for (int i = 0; i < NLAYERS; ++i) {
        {
            dim3 g(NPADIN / 128, 8192 / 128);
            k_hgemm<128, 0><<<g, 256, 0, stream>>>(
                hcur, w_in_h + (size_t)i * NPADIN * DMODEL, nullptr, zx16, dtraw,
                8192, DINPROJ, DMODEL, nullptr);
        }
        k_dwconv<<<(NB * LOUT * CDT) / 256, 256, 0, stream>>>(
            zx16, dtraw, dw_w + (size_t)i * CONVDIM * 4, dw_b + (size_t)i * CONVDIM,
            dt_bias + i * NHEADS, A_log + i * NHEADS, xbc16, dadt);
        k_ssd1<<<NB * NCHUNK * 4, 256, 0, stream>>>(xbc16, dadt, yss, Sbuf16, Abuf);
        k_hscan<<<NB * NHEADS * 4, 64, 0, stream>>>(Sbuf16, Abuf, H16);
        k_ssd2<<<NB * NCHUNK * NHEADS, 64, 0, stream>>>(xbc16, dadt, H16, y2);
        k_gate<<<NB * LOUT, 256, 0, stream>>>(zx16, xbc16, ssm_D + i * NHEADS,
                                              rms_w + (size_t)i * DINNER, yss, y2, ygate);
        {
            dim3 g(DMODEL / 128, 8192 / 64);
            k_hgemm<64, 0><<<g, 256, 0, stream>>>(
                ygate, w_out_h + (size_t)i * DMODEL * DINNER, hbuf, hnxt, nullptr,
                8192, DMODEL, DINNER, nullptr);
        }
        f16* tmp = hcur; hcur = hnxt; hnxt = tmp;
    }

    // final LN + pool + head
    k_zero<<<(NB * DMODEL + 255) / 256, 256, 0, stream>>>(pooled, NB * DMODEL);
    k_lnpool<<<NB * 32, 256, 0, stream>>>(hbuf, ln_w, ln_b, pooled);
    k_head<<<NB, 128, 0, stream>>>(pooled, reg1_w, reg1_b, reg2_w, reg2_b, (float*)d_out);
}

// Round 7
// 1289.066 us; speedup vs baseline: 2.6754x; 1.0375x over previous
//
#include <hip/hip_runtime.h>
#include <math.h>

#define NB       8
#define SEQ      8192
#define L1OUT    2048
#define LOUT     1024
#define DMODEL   256
#define DINNER   1024
#define NHEADS   16
#define HEADDIM  64
#define DSTATE   64
#define CONVDIM  1152
#define DINPROJ  2192
#define NPADIN   2304     // in_proj rows padded to multiple of 128
#define NLAYERS  8
#define NCHUNK   16
#define Q        64       // chunk length
#define CGRP     146      // 144 conv channel-groups of 8 + 2 dt groups

typedef _Float16 f16;
typedef __attribute__((ext_vector_type(8))) _Float16 f16x8;
typedef __attribute__((ext_vector_type(4))) _Float16 f16x4;
typedef __attribute__((ext_vector_type(4))) float    f32x4;

__device__ __forceinline__ float gelu_f(float v) {
    return 0.5f * v * (1.0f + erff(v * 0.70710678118654752f));
}
__device__ __forceinline__ float silu_f(float v) {
    return v / (1.0f + __expf(-v));
}

__device__ __forceinline__ void gload16(const void* g, void* l) {
    __builtin_amdgcn_global_load_lds(
        (const __attribute__((address_space(1))) unsigned int*)g,
        (__attribute__((address_space(3))) unsigned int*)l, 16, 0, 0);
}

// ---------------- weight casts ----------------
__global__ __launch_bounds__(256) void k_cast(const float* __restrict__ in,
                                              f16* __restrict__ out, int n) {
    int i = blockIdx.x * 256 + threadIdx.x;
    if (i < n) out[i] = (f16)in[i];
}

__global__ __launch_bounds__(256) void k_cast_inproj(const float* __restrict__ w,
                                                     f16* __restrict__ out) {
    int idx = blockIdx.x * 256 + threadIdx.x;       // 8*2304*256
    int c = idx & 255;
    int r = (idx >> 8) % NPADIN;
    int l = idx / (NPADIN * 256);
    float v = (r < DINPROJ) ? w[((size_t)l * DINPROJ + r) * 256 + c] : 0.f;
    out[idx] = (f16)v;
}

// ---------------- conv1 (3->64, k16, s4, pad6) + GELU -> f16 ----------------
__global__ __launch_bounds__(256) void k_conv1(const float* __restrict__ x,
                                               const float* __restrict__ w,
                                               const float* __restrict__ bias,
                                               f16* __restrict__ out) {
    int idx = blockIdx.x * 256 + threadIdx.x;      // NB*64*L1OUT
    int t  = idx & (L1OUT - 1);
    int co = (idx >> 11) & 63;
    int b  = idx >> 17;
    float s = bias[co];
#pragma unroll
    for (int ci = 0; ci < 3; ++ci) {
        const float* xp = x + ((size_t)b * 3 + ci) * SEQ;
        const float* wp = w + (co * 3 + ci) * 16;
#pragma unroll
        for (int k = 0; k < 16; ++k) {
            int pos = t * 4 + k - 6;
            if (pos >= 0 && pos < SEQ) s = fmaf(xp[pos], wp[k], s);
        }
    }
    out[idx] = (f16)gelu_f(s);
}

// ---------------- im2col for conv2 (64ch, k16, s2, pad7), f16 -> f16 ---------
__global__ __launch_bounds__(256) void k_im2col(const f16* __restrict__ h1,
                                                f16* __restrict__ A) {
    int idx = blockIdx.x * 256 + threadIdx.x;      // 8192*1024
    int col = idx & 1023;
    int row = idx >> 10;
    int t = row & (LOUT - 1);
    int b = row >> 10;
    int ci = col >> 4, k = col & 15;
    int pos = t * 2 + k - 7;
    f16 v = (f16)0.f;
    if (pos >= 0 && pos < L1OUT) v = h1[((size_t)b * 64 + ci) * L1OUT + pos];
    A[idx] = v;
}

// ---------------- fp16 MFMA GEMM: C[M,N] = A[M,K] * B[Npad,K]^T ----------------
// Dtr: optional compact fp32 copy of cols [DINNER+CONVDIM, DINPROJ) (dt raw).
template<int BM, int EPI>
__global__ __launch_bounds__(256) void k_hgemm(const f16* __restrict__ A,
                                               const f16* __restrict__ Bw,
                                               float* __restrict__ Cf,
                                               f16* __restrict__ Ch,
                                               float* __restrict__ Dtr,
                                               int M, int N, int K,
                                               const float* __restrict__ bias) {
    constexpr int MI = BM / 32;
    __shared__ f16 As[BM * 32];
    __shared__ f16 Bs[128 * 32];
    int tid  = threadIdx.x;
    int lane = tid & 63, wid = tid >> 6;
    int wm = wid >> 1, wn = wid & 1;
    int row0 = blockIdx.y * BM, col0 = blockIdx.x * 128;
    int lr = lane & 15, kb = lane >> 4;

    f32x4 acc[MI][4];
#pragma unroll
    for (int mi = 0; mi < MI; ++mi)
#pragma unroll
        for (int ni = 0; ni < 4; ++ni)
            acc[mi][ni] = (f32x4){0.f, 0.f, 0.f, 0.f};

    int srow = tid >> 2;
    int scol = (tid & 3) * 8;

    for (int k0 = 0; k0 < K; k0 += 32) {
        __syncthreads();
#pragma unroll
        for (int is = 0; is < BM / 64; ++is)
            gload16(A + (size_t)(row0 + is * 64 + srow) * K + k0 + scol,
                    &As[is * 2048 + wid * 512]);
#pragma unroll
        for (int is = 0; is < 2; ++is)
            gload16(Bw + (size_t)(col0 + is * 64 + srow) * K + k0 + scol,
                    &Bs[is * 2048 + wid * 512]);
        __syncthreads();

        f16x8 a[MI], b[4];
#pragma unroll
        for (int mi = 0; mi < MI; ++mi)
            a[mi] = *reinterpret_cast<const f16x8*>(
                &As[(wm * (BM / 2) + mi * 16 + lr) * 32 + kb * 8]);
#pragma unroll
        for (int ni = 0; ni < 4; ++ni)
            b[ni] = *reinterpret_cast<const f16x8*>(
                &Bs[(wn * 64 + ni * 16 + lr) * 32 + kb * 8]);
#pragma unroll
        for (int mi = 0; mi < MI; ++mi)
#pragma unroll
            for (int ni = 0; ni < 4; ++ni)
                acc[mi][ni] = __builtin_amdgcn_mfma_f32_16x16x32_f16(
                    a[mi], b[ni], acc[mi][ni], 0, 0, 0);
    }

#pragma unroll
    for (int mi = 0; mi < MI; ++mi)
#pragma unroll
        for (int ni = 0; ni < 4; ++ni) {
            int ccol = col0 + wn * 64 + ni * 16 + lr;
            if (ccol < N) {
                int rbase = row0 + wm * (BM / 2) + mi * 16 + kb * 4;
                f32x4 v = acc[mi][ni];
#pragma unroll
                for (int r = 0; r < 4; ++r) {
                    float val = v[r];
                    if (EPI == 1) val = gelu_f(val + bias[ccol]);
                    if (Cf) Cf[(size_t)(rbase + r) * N + ccol] = val;
                    if (Ch) Ch[(size_t)(rbase + r) * N + ccol] = (f16)val;
                    if (Dtr && ccol >= DINNER + CONVDIM)
                        Dtr[(size_t)(rbase + r) * 16 + (ccol - (DINNER + CONVDIM))] = val;
                }
            }
        }
}

// --- depthwise causal conv (k=4) + SiLU -> f16, vectorized 8ch/thread, ------
// --- fused dt/dA compute; XCD-chunked block swizzle (one batch per XCD) -----
__global__ __launch_bounds__(256) void k_dwconv(const f16* __restrict__ zx16,
                                                const float* __restrict__ dtraw,
                                                const float* __restrict__ w,
                                                const float* __restrict__ bias,
                                                const float* __restrict__ dt_bias,
                                                const float* __restrict__ A_log,
                                                f16* __restrict__ out16,
                                                float* __restrict__ dadt) {
    // grid = 4672 = 8 * 584; swizzle so XCD i gets contiguous idx range
    int bid = blockIdx.x;
    int swz = (bid & 7) * 584 + (bid >> 3);
    int idx = swz * 256 + threadIdx.x;             // NB*LOUT*CGRP
    int cg = idx % CGRP;
    int bl = idx / CGRP;
    int l  = bl & (LOUT - 1);
    if (cg < 144) {
        int c0 = cg * 8;
        float acc[8];
#pragma unroll
        for (int j = 0; j < 8; ++j) acc[j] = bias[c0 + j];
        float4 wv[8];
#pragma unroll
        for (int j = 0; j < 8; ++j) wv[j] = *(const float4*)&w[(c0 + j) * 4];
#pragma unroll
        for (int k = 0; k < 4; ++k) {
            int t = l - 3 + k;
            if (t >= 0) {
                f16x8 v = *(const f16x8*)&zx16[(size_t)(bl - 3 + k) * DINPROJ + DINNER + c0];
#pragma unroll
                for (int j = 0; j < 8; ++j) {
                    float wk = (k == 0) ? wv[j].x : (k == 1) ? wv[j].y
                             : (k == 2) ? wv[j].z : wv[j].w;
                    acc[j] = fmaf((float)v[j], wk, acc[j]);
                }
            }
        }
        f16x8 o;
#pragma unroll
        for (int j = 0; j < 8; ++j) o[j] = (f16)silu_f(acc[j]);
        *(f16x8*)&out16[(size_t)bl * CONVDIM + c0] = o;
    } else {
        int h0 = (cg - 144) * 8;
        float2 od[8];
#pragma unroll
        for (int j = 0; j < 8; ++j) {
            float raw = dtraw[bl * 16 + h0 + j] + dt_bias[h0 + j];
            float dtv = (raw > 20.f) ? raw : log1pf(__expf(raw));
            od[j] = make_float2(-__expf(A_log[h0 + j]) * dtv, dtv);
        }
#pragma unroll
        for (int j = 0; j < 8; ++j)
            *(float2*)&dadt[(size_t)(bl * 16 + h0 + j) * 2] = od[j];
    }
}

// ---------------- SSD part 1: per (b, chunk, 4 heads) ----------------
// stage B/C/X in LDS; G = C.B^T; per head: S = X^T.(w*B)^T (f16 out),
// M = masked decay * G, Y_intra = M.X -> y1 (f16)
__global__ __launch_bounds__(256) void k_ssd1(const f16* __restrict__ xbc16,
                                              const float* __restrict__ dadt,
                                              f16* __restrict__ y1,
                                              f16* __restrict__ Sbuf16,
                                              float* __restrict__ Abuf) {
    __shared__ f16 Bs[64][72];
    __shared__ f16 Cs[64][72];
    __shared__ float GT[64][68];            // GT[s][t]
    __shared__ f16 Mw[4][64][72];           // X staging, then per-wave sBT / M
    __shared__ float2 LaDt[4][64];

    int tid = threadIdx.x, lane = tid & 63, wid = tid >> 6;
    int bid = blockIdx.x;
    int hq = bid & 3, c = (bid >> 2) & 15, b = bid >> 6;
    int h = hq * 4 + wid;
    int lr = lane & 15, kb = lane >> 4;

    // stage B, C into LDS (padded rows)
    const f16* src = xbc16 + ((size_t)(b * 1024 + c * 64)) * CONVDIM + 1024;
#pragma unroll
    for (int it = 0; it < 4; ++it) {
        int cid = it * 256 + tid;
        int row = cid >> 4, off = (cid & 15) * 8;
        f16x8 v = *(const f16x8*)(src + (size_t)row * CONVDIM + off);
        if (off < 64) *(f16x8*)&Bs[row][off] = v;
        else          *(f16x8*)&Cs[row][off - 64] = v;
    }

    // stage X rows (4 heads worth) into Mw region: Xs[t][ch], pad 260
    f16* Xs = &Mw[0][0][0];
    const f16* xsrc = xbc16 + ((size_t)(b * 1024 + c * 64)) * CONVDIM + hq * 256;
#pragma unroll
    for (int it = 0; it < 8; ++it) {
        int cid = it * 256 + tid;
        int row = cid >> 5, chk = cid & 31;
        f16x4 v0 = *(const f16x4*)(xsrc + (size_t)row * CONVDIM + chk * 8);
        f16x4 v1 = *(const f16x4*)(xsrc + (size_t)row * CONVDIM + chk * 8 + 4);
        *(f16x4*)&Xs[row * 260 + chk * 8] = v0;
        *(f16x4*)&Xs[row * 260 + chk * 8 + 4] = v1;
    }

    // per-lane (lane = t): log-decay cumsum + dt
    float2 ad = *(const float2*)&dadt[((size_t)(b * 1024 + c * 64 + lane) * 16 + h) * 2];
    float La = ad.x;
#pragma unroll
    for (int o = 1; o < 64; o <<= 1) {
        float v = __shfl_up(La, o);
        if (lane >= o) La += v;
    }
    float dt_own = ad.y;
    float La63 = __shfl(La, 63);
    float w_own = __expf(La63 - La) * dt_own;   // state weight, <= dt
    LaDt[wid][lane] = make_float2(La, dt_own);
    __syncthreads();

    // read X^T fragments from LDS (row p, k=t)
    f16x8 xfrag[4][2];
#pragma unroll
    for (int pi = 0; pi < 4; ++pi)
#pragma unroll
        for (int ks = 0; ks < 2; ++ks) {
            f16x8 v;
#pragma unroll
            for (int j = 0; j < 8; ++j)
                v[j] = Xs[(ks * 32 + kb * 8 + j) * 260 + wid * 64 + pi * 16 + lr];
            xfrag[pi][ks] = v;
        }

    // G = C.B^T : each wave one 32x32 quadrant -> GT[s][t]
    {
        int tq = wid & 1, sq = wid >> 1;
        f32x4 g[2][2];
#pragma unroll
        for (int i = 0; i < 2; ++i)
#pragma unroll
            for (int j = 0; j < 2; ++j) g[i][j] = (f32x4){0.f, 0.f, 0.f, 0.f};
#pragma unroll
        for (int ks = 0; ks < 2; ++ks) {
            f16x8 a[2], bb[2];
#pragma unroll
            for (int ti = 0; ti < 2; ++ti)
                a[ti] = *(const f16x8*)&Cs[tq * 32 + ti * 16 + lr][ks * 32 + kb * 8];
#pragma unroll
            for (int si = 0; si < 2; ++si)
                bb[si] = *(const f16x8*)&Bs[sq * 32 + si * 16 + lr][ks * 32 + kb * 8];
#pragma unroll
            for (int ti = 0; ti < 2; ++ti)
#pragma unroll
                for (int si = 0; si < 2; ++si)
                    g[ti][si] = __builtin_amdgcn_mfma_f32_16x16x32_f16(
                        a[ti], bb[si], g[ti][si], 0, 0, 0);
        }
#pragma unroll
        for (int ti = 0; ti < 2; ++ti)
#pragma unroll
            for (int si = 0; si < 2; ++si)
#pragma unroll
                for (int r = 0; r < 4; ++r)
                    GT[sq * 32 + si * 16 + lr][tq * 32 + ti * 16 + kb * 4 + r] = g[ti][si][r];
    }
    __syncthreads();   // GT ready; all xfrag reads done -> Mw reusable

    // ---- head phase (wave-local) ----
    // sBT[n][t] = B[t][n] * w_t  into Mw[wid]
    {
        f16x8 brow[8];
#pragma unroll
        for (int i = 0; i < 8; ++i) brow[i] = *(const f16x8*)&Bs[lane][i * 8];
#pragma unroll
        for (int i = 0; i < 8; ++i)
#pragma unroll
            for (int j = 0; j < 8; ++j)
                Mw[wid][i * 8 + j][lane] = (f16)((float)brow[i][j] * w_own);
    }
    __builtin_amdgcn_wave_barrier();

    f16x8 sbfrag[4][2];
#pragma unroll
    for (int ni = 0; ni < 4; ++ni)
#pragma unroll
        for (int ks = 0; ks < 2; ++ks)
            sbfrag[ni][ks] = *(const f16x8*)&Mw[wid][ni * 16 + lr][ks * 32 + kb * 8];

    // S[p][n] = sum_t X^T[p][t] sBT[n][t]  -> f16
    {
        f32x4 accS[4][4];
#pragma unroll
        for (int pi = 0; pi < 4; ++pi)
#pragma unroll
            for (int ni = 0; ni < 4; ++ni) accS[pi][ni] = (f32x4){0.f, 0.f, 0.f, 0.f};
#pragma unroll
        for (int ks = 0; ks < 2; ++ks)
#pragma unroll
            for (int pi = 0; pi < 4; ++pi)
#pragma unroll
                for (int ni = 0; ni < 4; ++ni)
                    accS[pi][ni] = __builtin_amdgcn_mfma_f32_16x16x32_f16(
                        xfrag[pi][ks], sbfrag[ni][ks], accS[pi][ni], 0, 0, 0);
        size_t sbase = ((size_t)((b * 16 + h) * 16 + c)) << 12;
#pragma unroll
        for (int pi = 0; pi < 4; ++pi)
#pragma unroll
            for (int ni = 0; ni < 4; ++ni)
#pragma unroll
                for (int r = 0; r < 4; ++r)
                    Sbuf16[sbase + (size_t)(pi * 16 + kb * 4 + r) * 64 + ni * 16 + lr] =
                        (f16)accS[pi][ni][r];
        if (lane == 0) Abuf[(b * 16 + h) * 16 + c] = __expf(La63);
    }
    __builtin_amdgcn_wave_barrier();

    // M[t][s] = (s<=t) ? G[t][s]*exp(La_t-La_s)*dt_s : 0   (lane = t)
    {
        int t = lane;
        float la_t = La;
#pragma unroll
        for (int s8 = 0; s8 < 8; ++s8) {
            f16x8 mv;
#pragma unroll
            for (int j = 0; j < 8; ++j) {
                int s = s8 * 8 + j;
                float2 ld = LaDt[wid][s];
                float m = (s <= t) ? GT[s][t] * __expf(la_t - ld.x) * ld.y : 0.f;
                mv[j] = (f16)m;
            }
            *(f16x8*)&Mw[wid][t][s8 * 8] = mv;
        }
    }
    __builtin_amdgcn_wave_barrier();

    // Y_intra[t][p] = sum_s M[t][s] X[s][p]  -> f16
    {
        f32x4 accY[4][4];
#pragma unroll
        for (int ti = 0; ti < 4; ++ti)
#pragma unroll
            for (int pi = 0; pi < 4; ++pi) accY[ti][pi] = (f32x4){0.f, 0.f, 0.f, 0.f};
#pragma unroll
        for (int ks = 0; ks < 2; ++ks) {
            f16x8 af[4];
#pragma unroll
            for (int ti = 0; ti < 4; ++ti)
                af[ti] = *(const f16x8*)&Mw[wid][ti * 16 + lr][ks * 32 + kb * 8];
#pragma unroll
            for (int ti = 0; ti < 4; ++ti)
#pragma unroll
                for (int pi = 0; pi < 4; ++pi)
                    accY[ti][pi] = __builtin_amdgcn_mfma_f32_16x16x32_f16(
                        af[ti], xfrag[pi][ks], accY[ti][pi], 0, 0, 0);
        }
        f16* yp = y1 + ((size_t)(b * 1024 + c * 64)) * 1024 + h * 64;
#pragma unroll
        for (int ti = 0; ti < 4; ++ti)
#pragma unroll
            for (int pi = 0; pi < 4; ++pi)
#pragma unroll
                for (int r = 0; r < 4; ++r)
                    yp[(size_t)(ti * 16 + kb * 4 + r) * 1024 + pi * 16 + lr] =
                        (f16)accY[ti][pi][r];
    }
}

// ---------------- inter-chunk state recurrence (f16 S in, f16 H out) --------
__global__ __launch_bounds__(64) void k_hscan(const f16* __restrict__ Sbuf16,
                                              const float* __restrict__ Abuf,
                                              f16* __restrict__ H16) {
    int tid = threadIdx.x;
    int bid = blockIdx.x;                // 512: bh*4 + q
    int bh = bid >> 2, q = bid & 3;
    size_t base = (size_t)bh << 16;      // 16 chunks * 4096
    int off = q * 1024 + tid * 16;
    float Hl[16];
#pragma unroll
    for (int j = 0; j < 16; ++j) Hl[j] = 0.f;
    for (int c = 0; c < NCHUNK; ++c) {
        f16x8 o0, o1;
#pragma unroll
        for (int j = 0; j < 8; ++j) { o0[j] = (f16)Hl[j]; o1[j] = (f16)Hl[j + 8]; }
        *(f16x8*)&H16[base + (size_t)c * 4096 + off] = o0;
        *(f16x8*)&H16[base + (size_t)c * 4096 + off + 8] = o1;
        float A = Abuf[bh * 16 + c];
        f16x8 s0 = *(const f16x8*)&Sbuf16[base + (size_t)c * 4096 + off];
        f16x8 s1 = *(const f16x8*)&Sbuf16[base + (size_t)c * 4096 + off + 8];
#pragma unroll
        for (int j = 0; j < 8; ++j) {
            Hl[j]     = fmaf(Hl[j],     A, (float)s0[j]);
            Hl[j + 8] = fmaf(Hl[j + 8], A, (float)s1[j]);
        }
    }
}

// ------------- SSD part 2: y2 = exp(La_t) * (C . Hinit^T)  (f16 out) --------
__global__ __launch_bounds__(64) void k_ssd2(const f16* __restrict__ xbc16,
                                             const float* __restrict__ dadt,
                                             const f16* __restrict__ H16,
                                             f16* __restrict__ y2) {
    __shared__ f16 Csl[64][72];
    __shared__ float La64[64];
    int lane = threadIdx.x;
    int bid = blockIdx.x;               // b*256 + c*16 + h
    int h = bid & 15, c = (bid >> 4) & 15, b = bid >> 8;
    int lr = lane & 15, kb = lane >> 4;

    f16x8 hfrag[4][2];
    const f16* Hh = H16 + (((size_t)((b * 16 + h) * 16 + c)) << 12);
#pragma unroll
    for (int pi = 0; pi < 4; ++pi)
#pragma unroll
        for (int ks = 0; ks < 2; ++ks)
            hfrag[pi][ks] = *(const f16x8*)(Hh + (size_t)(pi * 16 + lr) * 64 + ks * 32 + kb * 8);

    const f16* csrc = xbc16 + ((size_t)(b * 1024 + c * 64 + lane)) * CONVDIM + 1024 + 64;
#pragma unroll
    for (int i = 0; i < 8; ++i)
        *(f16x8*)&Csl[lane][i * 8] = *(const f16x8*)(csrc + i * 8);

    float2 ad = *(const float2*)&dadt[((size_t)(b * 1024 + c * 64 + lane) * 16 + h) * 2];
    float La = ad.x;
#pragma unroll
    for (int o = 1; o < 64; o <<= 1) {
        float v = __shfl_up(La, o);
        if (lane >= o) La += v;
    }
    La64[lane] = La;
    __syncthreads();

    f32x4 acc[4][4];
#pragma unroll
    for (int ti = 0; ti < 4; ++ti)
#pragma unroll
        for (int pi = 0; pi < 4; ++pi) acc[ti][pi] = (f32x4){0.f, 0.f, 0.f, 0.f};
#pragma unroll
    for (int ks = 0; ks < 2; ++ks) {
        f16x8 af[4];
#pragma unroll
        for (int ti = 0; ti < 4; ++ti)
            af[ti] = *(const f16x8*)&Csl[ti * 16 + lr][ks * 32 + kb * 8];
#pragma unroll
        for (int ti = 0; ti < 4; ++ti)
#pragma unroll
            for (int pi = 0; pi < 4; ++pi)
                acc[ti][pi] = __builtin_amdgcn_mfma_f32_16x16x32_f16(
                    af[ti], hfrag[pi][ks], acc[ti][pi], 0, 0, 0);
    }
    f16* yp = y2 + ((size_t)(b * 1024 + c * 64)) * 1024 + h * 64;
#pragma unroll
    for (int ti = 0; ti < 4; ++ti)
#pragma unroll
        for (int r = 0; r < 4; ++r) {
            int t = ti * 16 + kb * 4 + r;
            float sc = __expf(La64[t]);
#pragma unroll
            for (int pi = 0; pi < 4; ++pi)
                yp[(size_t)t * 1024 + pi * 16 + lr] = (f16)(sc * acc[ti][pi][r]);
        }
}

// -- y = (y1 + y2 + D*xh) * silu(z); RMSNorm * rms_w; f16 out for out_proj --
__global__ __launch_bounds__(256) void k_gate(const f16* __restrict__ zx16,
                                              const f16* __restrict__ xbc16,
                                              const float* __restrict__ ssmD,
                                              const float* __restrict__ rmsw,
                                              const f16* __restrict__ y1,
                                              const f16* __restrict__ y2,
                                              f16* __restrict__ ygate) {
    __shared__ float sh[4];
    int bl = blockIdx.x, tid = threadIdx.x;
    int c = tid * 4;
    f16x4 y1v = *reinterpret_cast<const f16x4*>(&y1[(size_t)bl * DINNER + c]);
    f16x4 y2v = *reinterpret_cast<const f16x4*>(&y2[(size_t)bl * DINNER + c]);
    f16x4 xh4 = *reinterpret_cast<const f16x4*>(&xbc16[(size_t)bl * CONVDIM + c]);
    f16x4 z4  = *reinterpret_cast<const f16x4*>(&zx16[(size_t)bl * DINPROJ + c]);
    float Dv = ssmD[tid >> 4];
    float v[4];
    float ss = 0.f;
#pragma unroll
    for (int j = 0; j < 4; ++j) {
        v[j] = ((float)y1v[j] + (float)y2v[j] + Dv * (float)xh4[j]) * silu_f((float)z4[j]);
        ss += v[j] * v[j];
    }
    int lane = tid & 63, wid = tid >> 6;
#pragma unroll
    for (int o = 32; o > 0; o >>= 1) ss += __shfl_down(ss, o, 64);
    if (lane == 0) sh[wid] = ss;
    __syncthreads();
    float total = sh[0] + sh[1] + sh[2] + sh[3];
    float r = rsqrtf(total * (1.f / DINNER) + 1e-5f);
    f16x4 o4;
    o4.x = (f16)(v[0] * r * rmsw[c + 0]);
    o4.y = (f16)(v[1] * r * rmsw[c + 1]);
    o4.z = (f16)(v[2] * r * rmsw[c + 2]);
    o4.w = (f16)(v[3] * r * rmsw[c + 3]);
    *reinterpret_cast<f16x4*>(&ygate[(size_t)bl * DINNER + c]) = o4;
}

// ------- final LayerNorm + mean pool: wave-per-row, block partial, 1 atomic --
__global__ __launch_bounds__(256) void k_lnpool(const f16* __restrict__ h,
                                                const float* __restrict__ lnw,
                                                const float* __restrict__ lnb,
                                                float* __restrict__ pooled) {
    __shared__ float pl[4][256];
    int bid = blockIdx.x;                // 8 * 32
    int b = bid >> 5, seg = bid & 31;
    int tid = threadIdx.x, lane = tid & 63, w = tid >> 6;
    int c4 = lane * 4;
    float4 lw = *(const float4*)&lnw[c4];
    float4 lb = *(const float4*)&lnb[c4];
    float acc0 = 0.f, acc1 = 0.f, acc2 = 0.f, acc3 = 0.f;
    const f16* hb = h + ((size_t)b * 1024 + seg * 32 + w * 8) * DMODEL;
#pragma unroll
    for (int i = 0; i < 8; ++i) {
        f16x4 hv = *(const f16x4*)(hb + (size_t)i * DMODEL + c4);
        float vx = (float)hv.x, vy = (float)hv.y, vz = (float)hv.z, vw = (float)hv.w;
        float s1 = vx + vy + vz + vw;
        float s2 = vx * vx + vy * vy + vz * vz + vw * vw;
#pragma unroll
        for (int o = 32; o > 0; o >>= 1) {
            s1 += __shfl_xor(s1, o);
            s2 += __shfl_xor(s2, o);
        }
        float mu = s1 * (1.f / DMODEL);
        float var = s2 * (1.f / DMODEL) - mu * mu;
        float rr = rsqrtf(var + 1e-5f);
        acc0 += (vx - mu) * rr * lw.x + lb.x;
        acc1 += (vy - mu) * rr * lw.y + lb.y;
        acc2 += (vz - mu) * rr * lw.z + lb.z;
        acc3 += (vw - mu) * rr * lw.w + lb.w;
    }
    pl[w][c4 + 0] = acc0; pl[w][c4 + 1] = acc1;
    pl[w][c4 + 2] = acc2; pl[w][c4 + 3] = acc3;
    __syncthreads();
    float tot = pl[0][tid] + pl[1][tid] + pl[2][tid] + pl[3][tid];
    atomicAdd(&pooled[b * DMODEL + tid], tot * (1.f / LOUT));
}

__global__ void k_zero(float* __restrict__ p, int n) {
    int i = blockIdx.x * 256 + threadIdx.x;
    if (i < n) p[i] = 0.f;
}

// ---------------- regression head ----------------
__global__ __launch_bounds__(128) void k_head(const float* __restrict__ pooled,
                                              const float* __restrict__ w1,
                                              const float* __restrict__ b1,
                                              const float* __restrict__ w2,
                                              const float* __restrict__ b2,
                                              float* __restrict__ out) {
    __shared__ float red[2];
    int b = blockIdx.x, j = threadIdx.x;
    float acc = b1[j];
#pragma unroll 8
    for (int d = 0; d < DMODEL; ++d)
        acc = fmaf(pooled[b * DMODEL + d], w1[j * DMODEL + d], acc);
    float r = gelu_f(acc) * w2[j];
#pragma unroll
    for (int o = 32; o > 0; o >>= 1) r += __shfl_down(r, o, 64);
    int lane = j & 63, wid = j >> 6;
    if (lane == 0) red[wid] = r;
    __syncthreads();
    if (j == 0) out[b] = red[0] + red[1] + b2[0];
}

extern "C" void kernel_launch(void* const* d_in, const int* in_sizes, int n_in,
                              void* d_out, int out_size, void* d_ws, size_t ws_size,
                              hipStream_t stream) {
    const float* x         = (const float*)d_in[0];
    const float* conv1_w   = (const float*)d_in[1];
    const float* conv1_b   = (const float*)d_in[2];
    const float* conv2_w   = (const float*)d_in[3];
    const float* conv2_b   = (const float*)d_in[4];
    const float* in_proj_w = (const float*)d_in[5];
    const float* dw_w      = (const float*)d_in[6];
    const float* dw_b      = (const float*)d_in[7];
    const float* dt_bias   = (const float*)d_in[8];
    const float* A_log     = (const float*)d_in[9];
    const float* ssm_D     = (const float*)d_in[10];
    const float* rms_w     = (const float*)d_in[11];
    const float* out_proj_w= (const float*)d_in[12];
    const float* ln_w      = (const float*)d_in[13];
    const float* ln_b      = (const float*)d_in[14];
    const float* reg1_w    = (const float*)d_in[15];
    const float* reg1_b    = (const float*)d_in[16];
    const float* reg2_w    = (const float*)d_in[17];
    const float* reg2_b    = (const float*)d_in[18];

    float* ws = (float*)d_ws;
    size_t off = 0;
    float* dtraw  = ws + off; off += (size_t)NB * LOUT * 16;        // 131,072
    float* dadt   = ws + off; off += (size_t)NB * LOUT * NHEADS * 2;// 262,144
    float* Abuf   = ws + off; off += (size_t)NB * NHEADS * NCHUNK;  // 2,048
    float* pooled = ws + off; off += NB * DMODEL;                   // 2,048

    f16* fbase = (f16*)(ws + off);
    size_t foff = 0;
    f16* c1f16  = fbase + foff; foff += (size_t)NB * 64 * L1OUT;
    f16* hbf0   = fbase + foff; foff += (size_t)NB * LOUT * DMODEL;
    f16* hbf1   = fbase + foff; foff += (size_t)NB * LOUT * DMODEL;
    f16* ygate  = fbase + foff; foff += (size_t)NB * LOUT * DINNER;   // also H16
    f16* y2     = fbase + foff; foff += (size_t)NB * LOUT * DINNER;
    f16* y1     = fbase + foff; foff += (size_t)NB * LOUT * DINNER;   // also im2h
    f16* xbc16  = fbase + foff; foff += (size_t)NB * LOUT * CONVDIM;
    f16* zx16   = fbase + foff; foff += (size_t)NB * LOUT * DINPROJ;
    f16* Sbuf16 = fbase + foff; foff += (size_t)NB * NHEADS * NCHUNK * 4096;
    f16* w_in_h = fbase + foff; foff += (size_t)NLAYERS * NPADIN * DMODEL;
    f16* w_out_h= fbase + foff; foff += (size_t)NLAYERS * DMODEL * DINNER;
    f16* w_c2_h = fbase + foff; foff += (size_t)DMODEL * 1024;
    f16* H16    = ygate;       // aliased: H16 dead before k_gate writes ygate
    f16* im2h   = y1;          // aliased: im2col dead before y1 first written

    // weight casts
    k_cast_inproj<<<(NLAYERS * NPADIN * 256) / 256, 256, 0, stream>>>(in_proj_w, w_in_h);
    k_cast<<<(NLAYERS * DMODEL * DINNER) / 256, 256, 0, stream>>>(
        out_proj_w, w_out_h, NLAYERS * DMODEL * DINNER);
    k_cast<<<(DMODEL * 1024) / 256, 256, 0, stream>>>(conv2_w, w_c2_h, DMODEL * 1024);

    // front-end convs
    k_conv1<<<(NB * 64 * L1OUT) / 256, 256, 0, stream>>>(x, conv1_w, conv1_b, c1f16);
    k_im2col<<<(NB * LOUT * 1024) / 256, 256, 0, stream>>>(c1f16, im2h);
    {
        dim3 g(256 / 128, 8192 / 64);
        k_hgemm<64, 1><<<g, 256, 0, stream>>>(im2h, w_c2_h, nullptr, hbf0, nullptr,
                                              8192, 256, 1024, conv2_b);
    }

    f16* hcur = hbf0;
    f16* hnxt = hbf1;
    for (int i = 0; i < NLAYERS; ++i) {
        {
            dim3 g(NPADIN / 128, 8192 / 128);
            k_hgemm<128, 0><<<g, 256, 0, stream>>>(
                hcur, w_in_h + (size_t)i * NPADIN * DMODEL, nullptr, zx16, dtraw,
                8192, DINPROJ, DMODEL, nullptr);
        }
        k_dwconv<<<(NB * LOUT * CGRP) / 256, 256, 0, stream>>>(
            zx16, dtraw, dw_w + (size_t)i * CONVDIM * 4, dw_b + (size_t)i * CONVDIM,
            dt_bias + i * NHEADS, A_log + i * NHEADS, xbc16, dadt);
        k_ssd1<<<NB * NCHUNK * 4, 256, 0, stream>>>(xbc16, dadt, y1, Sbuf16, Abuf);
        k_hscan<<<NB * NHEADS * 4, 64, 0, stream>>>(Sbuf16, Abuf, H16);
        k_ssd2<<<NB * NCHUNK * NHEADS, 64, 0, stream>>>(xbc16, dadt, H16, y2);
        k_gate<<<NB * LOUT, 256, 0, stream>>>(zx16, xbc16, ssm_D + i * NHEADS,
                                              rms_w + (size_t)i * DINNER, y1, y2, ygate);
        {
            dim3 g(DMODEL / 128, 8192 / 64);
            k_hgemm<64, 0><<<g, 256, 0, stream>>>(
                ygate, w_out_h + (size_t)i * DMODEL * DINNER, nullptr, hnxt, nullptr,
                8192, DMODEL, DINNER, nullptr);
        }
        f16* tmp = hcur; hcur = hnxt; hnxt = tmp;
    }

    // final LN + pool + head
    k_zero<<<(NB * DMODEL + 255) / 256, 256, 0, stream>>>(pooled, NB * DMODEL);
    k_lnpool<<<NB * 32, 256, 0, stream>>>(hcur, ln_w, ln_b, pooled);
    k_head<<<NB, 128, 0, stream>>>(pooled, reg1_w, reg1_b, reg2_w, reg2_b, (float*)d_out);
}

// Round 8
// 944.373 us; speedup vs baseline: 3.6519x; 1.3650x over previous
//
#include <hip/hip_runtime.h>
#include <math.h>

#define NB       8
#define SEQ      8192
#define L1OUT    2048
#define LOUT     1024
#define DMODEL   256
#define DINNER   1024
#define NHEADS   16
#define HEADDIM  64
#define DSTATE   64
#define CONVDIM  1152
#define DINPROJ  2192
#define NPADIN   2304     // in_proj rows padded to multiple of 128
#define NLAYERS  8
#define NCHUNK   16
#define Q        64       // chunk length

typedef _Float16 f16;
typedef __attribute__((ext_vector_type(8))) _Float16 f16x8;
typedef __attribute__((ext_vector_type(4))) _Float16 f16x4;
typedef __attribute__((ext_vector_type(4))) float    f32x4;

__device__ __forceinline__ float gelu_f(float v) {
    return 0.5f * v * (1.0f + erff(v * 0.70710678118654752f));
}
__device__ __forceinline__ float silu_f(float v) {
    return v * __builtin_amdgcn_rcpf(1.0f + __expf(-v));
}

__device__ __forceinline__ void gload16(const void* g, void* l) {
    __builtin_amdgcn_global_load_lds(
        (const __attribute__((address_space(1))) unsigned int*)g,
        (__attribute__((address_space(3))) unsigned int*)l, 16, 0, 0);
}

// ---------------- weight casts ----------------
__global__ __launch_bounds__(256) void k_cast(const float* __restrict__ in,
                                              f16* __restrict__ out, int n) {
    int i = blockIdx.x * 256 + threadIdx.x;
    if (i < n) out[i] = (f16)in[i];
}

__global__ __launch_bounds__(256) void k_cast_inproj(const float* __restrict__ w,
                                                     f16* __restrict__ out) {
    int idx = blockIdx.x * 256 + threadIdx.x;       // 8*2304*256
    int c = idx & 255;
    int r = (idx >> 8) % NPADIN;
    int l = idx / (NPADIN * 256);
    float v = (r < DINPROJ) ? w[((size_t)l * DINPROJ + r) * 256 + c] : 0.f;
    out[idx] = (f16)v;
}

// ---------------- conv1 (3->64, k16, s4, pad6) + GELU -> f16 ----------------
__global__ __launch_bounds__(256) void k_conv1(const float* __restrict__ x,
                                               const float* __restrict__ w,
                                               const float* __restrict__ bias,
                                               f16* __restrict__ out) {
    int idx = blockIdx.x * 256 + threadIdx.x;      // NB*64*L1OUT
    int t  = idx & (L1OUT - 1);
    int co = (idx >> 11) & 63;
    int b  = idx >> 17;
    float s = bias[co];
#pragma unroll
    for (int ci = 0; ci < 3; ++ci) {
        const float* xp = x + ((size_t)b * 3 + ci) * SEQ;
        const float* wp = w + (co * 3 + ci) * 16;
#pragma unroll
        for (int k = 0; k < 16; ++k) {
            int pos = t * 4 + k - 6;
            if (pos >= 0 && pos < SEQ) s = fmaf(xp[pos], wp[k], s);
        }
    }
    out[idx] = (f16)gelu_f(s);
}

// ---------------- im2col for conv2 (64ch, k16, s2, pad7), f16 -> f16 ---------
__global__ __launch_bounds__(256) void k_im2col(const f16* __restrict__ h1,
                                                f16* __restrict__ A) {
    int idx = blockIdx.x * 256 + threadIdx.x;      // 8192*1024
    int col = idx & 1023;
    int row = idx >> 10;
    int t = row & (LOUT - 1);
    int b = row >> 10;
    int ci = col >> 4, k = col & 15;
    int pos = t * 2 + k - 7;
    f16 v = (f16)0.f;
    if (pos >= 0 && pos < L1OUT) v = h1[((size_t)b * 64 + ci) * L1OUT + pos];
    A[idx] = v;
}

// ---------------- fp16 MFMA GEMM: C[M,N] = A[M,K] * B[Npad,K]^T ----------------
// EPI 0: plain f16 store; 1: gelu(v+bias) f16; 2: f16 store + dt columns ->
// dadt (softplus + decay) for ccol in [DINNER+CONVDIM, DINPROJ).
template<int BM, int EPI>
__global__ __launch_bounds__(256) void k_hgemm(const f16* __restrict__ A,
                                               const f16* __restrict__ Bw,
                                               f16* __restrict__ Ch,
                                               int M, int N, int K,
                                               const float* __restrict__ bias,
                                               const float* __restrict__ dt_bias,
                                               const float* __restrict__ A_log,
                                               float* __restrict__ dadt) {
    constexpr int MI = BM / 32;
    __shared__ f16 As[BM * 32];
    __shared__ f16 Bs[128 * 32];
    int tid  = threadIdx.x;
    int lane = tid & 63, wid = tid >> 6;
    int wm = wid >> 1, wn = wid & 1;
    int row0 = blockIdx.y * BM, col0 = blockIdx.x * 128;
    int lr = lane & 15, kb = lane >> 4;

    f32x4 acc[MI][4];
#pragma unroll
    for (int mi = 0; mi < MI; ++mi)
#pragma unroll
        for (int ni = 0; ni < 4; ++ni)
            acc[mi][ni] = (f32x4){0.f, 0.f, 0.f, 0.f};

    int srow = tid >> 2;
    int scol = (tid & 3) * 8;

    for (int k0 = 0; k0 < K; k0 += 32) {
        __syncthreads();
#pragma unroll
        for (int is = 0; is < BM / 64; ++is)
            gload16(A + (size_t)(row0 + is * 64 + srow) * K + k0 + scol,
                    &As[is * 2048 + wid * 512]);
#pragma unroll
        for (int is = 0; is < 2; ++is)
            gload16(Bw + (size_t)(col0 + is * 64 + srow) * K + k0 + scol,
                    &Bs[is * 2048 + wid * 512]);
        __syncthreads();

        f16x8 a[MI], b[4];
#pragma unroll
        for (int mi = 0; mi < MI; ++mi)
            a[mi] = *reinterpret_cast<const f16x8*>(
                &As[(wm * (BM / 2) + mi * 16 + lr) * 32 + kb * 8]);
#pragma unroll
        for (int ni = 0; ni < 4; ++ni)
            b[ni] = *reinterpret_cast<const f16x8*>(
                &Bs[(wn * 64 + ni * 16 + lr) * 32 + kb * 8]);
#pragma unroll
        for (int mi = 0; mi < MI; ++mi)
#pragma unroll
            for (int ni = 0; ni < 4; ++ni)
                acc[mi][ni] = __builtin_amdgcn_mfma_f32_16x16x32_f16(
                    a[mi], b[ni], acc[mi][ni], 0, 0, 0);
    }

#pragma unroll
    for (int mi = 0; mi < MI; ++mi)
#pragma unroll
        for (int ni = 0; ni < 4; ++ni) {
            int ccol = col0 + wn * 64 + ni * 16 + lr;
            if (ccol < N) {
                int rbase = row0 + wm * (BM / 2) + mi * 16 + kb * 4;
                f32x4 v = acc[mi][ni];
#pragma unroll
                for (int r = 0; r < 4; ++r) {
                    float val = v[r];
                    if (EPI == 1) val = gelu_f(val + bias[ccol]);
                    Ch[(size_t)(rbase + r) * N + ccol] = (f16)val;
                    if (EPI == 2 && ccol >= DINNER + CONVDIM) {
                        int hh = ccol - (DINNER + CONVDIM);
                        float raw = val + dt_bias[hh];
                        float dtv = (raw > 20.f) ? raw : log1pf(__expf(raw));
                        float lda = -__expf(A_log[hh]) * dtv;
                        *(float2*)&dadt[(size_t)(rbase + r) * 32 + hh * 2] =
                            make_float2(lda, dtv);
                    }
                }
            }
        }
}

// ---------------- SSD part 1: per (b, chunk, 4 heads) ----------------
// Fused depthwise conv+SiLU staging of B/C/X from zx16; G = C.B^T;
// per head: S = X^T.(w*B)^T (f16), M = masked decay*G (+D on diag),
// Y_intra = M.X -> y1 (f16). hq==0 also writes conv'd C to C16 for ssd2.
__global__ __launch_bounds__(256) void k_ssd1(const f16* __restrict__ zx16,
                                              const float* __restrict__ dadt,
                                              const float* __restrict__ dw_w,
                                              const float* __restrict__ dw_b,
                                              const float* __restrict__ ssmD,
                                              f16* __restrict__ y1,
                                              f16* __restrict__ Sbuf16,
                                              float* __restrict__ Abuf,
                                              f16* __restrict__ C16) {
    __shared__ f16 Bs[64][72];
    __shared__ f16 Cs[64][72];
    __shared__ float GT[64][68];            // GT[s][t]
    __shared__ f16 Mw[4][64][72];           // X staging, then per-wave sBT / M
    __shared__ float2 LaDt[4][64];

    int tid = threadIdx.x, lane = tid & 63, wid = tid >> 6;
    int bid = blockIdx.x;
    int hq = bid & 3, c = (bid >> 2) & 15, b = bid >> 6;
    int h = hq * 4 + wid;
    int lr = lane & 15, kb = lane >> 4;
    f16* Xs = &Mw[0][0][0];                 // [64][260] f16 (33,280 B)

    // ---- fused conv+SiLU staging: threads 0..191 own (ch-group, 16-t slice)
    {
        int sg = tid % 48;                  // 0..31 X, 32..39 B, 40..47 C
        int ts = tid / 48;                  // t-slice (use 0..3)
        if (ts < 4) {
            int xc;                         // xbc-channel base (weight index)
            if (sg < 32)      xc = hq * 256 + sg * 8;
            else if (sg < 40) xc = 1024 + (sg - 32) * 8;
            else              xc = 1088 + (sg - 40) * 8;
            int zc = 1024 + xc;             // zx16 column
            float4 wv[8];
            float  bv[8];
#pragma unroll
            for (int j = 0; j < 8; ++j) {
                wv[j] = *(const float4*)&dw_w[(xc + j) * 4];
                bv[j] = dw_b[xc + j];
            }
            int l0 = c * 64 + ts * 16;      // in-batch row of first output
            const f16* zrow = zx16 + ((size_t)(b * 1024 + l0)) * DINPROJ + zc;
            f16x8 r0, r1, r2, r3;
            f16x8 zz;
#pragma unroll
            for (int j = 0; j < 8; ++j) zz[j] = (f16)0.f;
            r0 = (l0 >= 3) ? *(const f16x8*)(zrow - 3 * DINPROJ) : zz;
            r1 = (l0 >= 2) ? *(const f16x8*)(zrow - 2 * DINPROJ) : zz;
            r2 = (l0 >= 1) ? *(const f16x8*)(zrow - 1 * DINPROJ) : zz;
#pragma unroll
            for (int t = 0; t < 16; ++t) {
                r3 = *(const f16x8*)(zrow + t * DINPROJ);
                f16x8 o;
#pragma unroll
                for (int j = 0; j < 8; ++j) {
                    float s = bv[j];
                    s = fmaf((float)r0[j], wv[j].x, s);
                    s = fmaf((float)r1[j], wv[j].y, s);
                    s = fmaf((float)r2[j], wv[j].z, s);
                    s = fmaf((float)r3[j], wv[j].w, s);
                    o[j] = (f16)silu_f(s);
                }
                int row = ts * 16 + t;
                if (sg < 32) {
                    // Xs row stride 260 f16 (520 B) -> 8B-aligned only: two x4
                    f16x4 o0 = {o[0], o[1], o[2], o[3]};
                    f16x4 o1 = {o[4], o[5], o[6], o[7]};
                    *(f16x4*)&Xs[row * 260 + sg * 8]     = o0;
                    *(f16x4*)&Xs[row * 260 + sg * 8 + 4] = o1;
                } else if (sg < 40) {
                    *(f16x8*)&Bs[row][(sg - 32) * 8] = o;
                } else {
                    *(f16x8*)&Cs[row][(sg - 40) * 8] = o;
                }
                r0 = r1; r1 = r2; r2 = r3;
            }
        }
    }

    // per-lane (lane = t): log-decay cumsum + dt (independent of staging)
    float2 ad = *(const float2*)&dadt[((size_t)(b * 1024 + c * 64 + lane) * 16 + h) * 2];
    float La = ad.x;
#pragma unroll
    for (int o = 1; o < 64; o <<= 1) {
        float v = __shfl_up(La, o);
        if (lane >= o) La += v;
    }
    float dt_own = ad.y;
    float La63 = __shfl(La, 63);
    float w_own = __expf(La63 - La) * dt_own;   // state weight, <= dt
    LaDt[wid][lane] = make_float2(La, dt_own);
    float Dh = ssmD[h];
    __syncthreads();

    // export conv'd C for ssd2 (one hq per (b,c))
    if (hq == 0) {
        f16* cp = C16 + (((size_t)(b * 16 + c)) << 12);
#pragma unroll
        for (int it = 0; it < 2; ++it) {
            int cid = it * 256 + tid;
            int row = cid >> 3, off = (cid & 7) * 8;
            *(f16x8*)&cp[row * 64 + off] = *(const f16x8*)&Cs[row][off];
        }
    }

    // read X^T fragments from LDS (row p, k=t)
    f16x8 xfrag[4][2];
#pragma unroll
    for (int pi = 0; pi < 4; ++pi)
#pragma unroll
        for (int ks = 0; ks < 2; ++ks) {
            f16x8 v;
#pragma unroll
            for (int j = 0; j < 8; ++j)
                v[j] = Xs[(ks * 32 + kb * 8 + j) * 260 + wid * 64 + pi * 16 + lr];
            xfrag[pi][ks] = v;
        }

    // G = C.B^T : each wave one 32x32 quadrant -> GT[s][t]
    {
        int tq = wid & 1, sq = wid >> 1;
        f32x4 g[2][2];
#pragma unroll
        for (int i = 0; i < 2; ++i)
#pragma unroll
            for (int j = 0; j < 2; ++j) g[i][j] = (f32x4){0.f, 0.f, 0.f, 0.f};
#pragma unroll
        for (int ks = 0; ks < 2; ++ks) {
            f16x8 a[2], bb[2];
#pragma unroll
            for (int ti = 0; ti < 2; ++ti)
                a[ti] = *(const f16x8*)&Cs[tq * 32 + ti * 16 + lr][ks * 32 + kb * 8];
#pragma unroll
            for (int si = 0; si < 2; ++si)
                bb[si] = *(const f16x8*)&Bs[sq * 32 + si * 16 + lr][ks * 32 + kb * 8];
#pragma unroll
            for (int ti = 0; ti < 2; ++ti)
#pragma unroll
                for (int si = 0; si < 2; ++si)
                    g[ti][si] = __builtin_amdgcn_mfma_f32_16x16x32_f16(
                        a[ti], bb[si], g[ti][si], 0, 0, 0);
        }
#pragma unroll
        for (int ti = 0; ti < 2; ++ti)
#pragma unroll
            for (int si = 0; si < 2; ++si)
#pragma unroll
                for (int r = 0; r < 4; ++r)
                    GT[sq * 32 + si * 16 + lr][tq * 32 + ti * 16 + kb * 4 + r] = g[ti][si][r];
    }
    __syncthreads();   // GT ready; all xfrag reads done -> Mw reusable

    // ---- head phase (wave-local) ----
    // sBT[n][t] = B[t][n] * w_t  into Mw[wid]
    {
        f16x8 brow[8];
#pragma unroll
        for (int i = 0; i < 8; ++i) brow[i] = *(const f16x8*)&Bs[lane][i * 8];
#pragma unroll
        for (int i = 0; i < 8; ++i)
#pragma unroll
            for (int j = 0; j < 8; ++j)
                Mw[wid][i * 8 + j][lane] = (f16)((float)brow[i][j] * w_own);
    }
    __builtin_amdgcn_wave_barrier();

    f16x8 sbfrag[4][2];
#pragma unroll
    for (int ni = 0; ni < 4; ++ni)
#pragma unroll
        for (int ks = 0; ks < 2; ++ks)
            sbfrag[ni][ks] = *(const f16x8*)&Mw[wid][ni * 16 + lr][ks * 32 + kb * 8];

    // S[p][n] = sum_t X^T[p][t] sBT[n][t]  -> f16
    {
        f32x4 accS[4][4];
#pragma unroll
        for (int pi = 0; pi < 4; ++pi)
#pragma unroll
            for (int ni = 0; ni < 4; ++ni) accS[pi][ni] = (f32x4){0.f, 0.f, 0.f, 0.f};
#pragma unroll
        for (int ks = 0; ks < 2; ++ks)
#pragma unroll
            for (int pi = 0; pi < 4; ++pi)
#pragma unroll
                for (int ni = 0; ni < 4; ++ni)
                    accS[pi][ni] = __builtin_amdgcn_mfma_f32_16x16x32_f16(
                        xfrag[pi][ks], sbfrag[ni][ks], accS[pi][ni], 0, 0, 0);
        size_t sbase = ((size_t)((b * 16 + h) * 16 + c)) << 12;
#pragma unroll
        for (int pi = 0; pi < 4; ++pi)
#pragma unroll
            for (int ni = 0; ni < 4; ++ni)
#pragma unroll
                for (int r = 0; r < 4; ++r)
                    Sbuf16[sbase + (size_t)(pi * 16 + kb * 4 + r) * 64 + ni * 16 + lr] =
                        (f16)accS[pi][ni][r];
        if (lane == 0) Abuf[(b * 16 + h) * 16 + c] = __expf(La63);
    }
    __builtin_amdgcn_wave_barrier();

    // M[t][s] = (s<=t) ? G[t][s]*exp(La_t-La_s)*dt_s : 0 ; M[t][t] += D_h
    {
        int t = lane;
        float la_t = La;
#pragma unroll
        for (int s8 = 0; s8 < 8; ++s8) {
            f16x8 mv;
#pragma unroll
            for (int j = 0; j < 8; ++j) {
                int s = s8 * 8 + j;
                float2 ld = LaDt[wid][s];
                float m = (s <= t) ? GT[s][t] * __expf(la_t - ld.x) * ld.y : 0.f;
                if (s == t) m += Dh;
                mv[j] = (f16)m;
            }
            *(f16x8*)&Mw[wid][t][s8 * 8] = mv;
        }
    }
    __builtin_amdgcn_wave_barrier();

    // Y_intra[t][p] = sum_s M[t][s] X[s][p]  -> f16 (includes D*xh)
    {
        f32x4 accY[4][4];
#pragma unroll
        for (int ti = 0; ti < 4; ++ti)
#pragma unroll
            for (int pi = 0; pi < 4; ++pi) accY[ti][pi] = (f32x4){0.f, 0.f, 0.f, 0.f};
#pragma unroll
        for (int ks = 0; ks < 2; ++ks) {
            f16x8 af[4];
#pragma unroll
            for (int ti = 0; ti < 4; ++ti)
                af[ti] = *(const f16x8*)&Mw[wid][ti * 16 + lr][ks * 32 + kb * 8];
#pragma unroll
            for (int ti = 0; ti < 4; ++ti)
#pragma unroll
                for (int pi = 0; pi < 4; ++pi)
                    accY[ti][pi] = __builtin_amdgcn_mfma_f32_16x16x32_f16(
                        af[ti], xfrag[pi][ks], accY[ti][pi], 0, 0, 0);
        }
        f16* yp = y1 + ((size_t)(b * 1024 + c * 64)) * 1024 + h * 64;
#pragma unroll
        for (int ti = 0; ti < 4; ++ti)
#pragma unroll
            for (int pi = 0; pi < 4; ++pi)
#pragma unroll
                for (int r = 0; r < 4; ++r)
                    yp[(size_t)(ti * 16 + kb * 4 + r) * 1024 + pi * 16 + lr] =
                        (f16)accY[ti][pi][r];
    }
}

// ---------------- inter-chunk state recurrence (f16 S in, f16 H out) --------
__global__ __launch_bounds__(64) void k_hscan(const f16* __restrict__ Sbuf16,
                                              const float* __restrict__ Abuf,
                                              f16* __restrict__ H16) {
    int tid = threadIdx.x;
    int bid = blockIdx.x;                // 512: bh*4 + q
    int bh = bid >> 2, q = bid & 3;
    size_t base = (size_t)bh << 16;      // 16 chunks * 4096
    int off = q * 1024 + tid * 16;
    float Hl[16];
#pragma unroll
    for (int j = 0; j < 16; ++j) Hl[j] = 0.f;
    for (int c = 0; c < NCHUNK; ++c) {
        f16x8 o0, o1;
#pragma unroll
        for (int j = 0; j < 8; ++j) { o0[j] = (f16)Hl[j]; o1[j] = (f16)Hl[j + 8]; }
        *(f16x8*)&H16[base + (size_t)c * 4096 + off] = o0;
        *(f16x8*)&H16[base + (size_t)c * 4096 + off + 8] = o1;
        float A = Abuf[bh * 16 + c];
        f16x8 s0 = *(const f16x8*)&Sbuf16[base + (size_t)c * 4096 + off];
        f16x8 s1 = *(const f16x8*)&Sbuf16[base + (size_t)c * 4096 + off + 8];
#pragma unroll
        for (int j = 0; j < 8; ++j) {
            Hl[j]     = fmaf(Hl[j],     A, (float)s0[j]);
            Hl[j + 8] = fmaf(Hl[j + 8], A, (float)s1[j]);
        }
    }
}

// ------------- SSD part 2: y2 = exp(La_t) * (C . Hinit^T)  (f16 out) --------
__global__ __launch_bounds__(64) void k_ssd2(const f16* __restrict__ C16,
                                             const float* __restrict__ dadt,
                                             const f16* __restrict__ H16,
                                             f16* __restrict__ y2) {
    __shared__ float La64[64];
    int lane = threadIdx.x;
    int bid = blockIdx.x;               // b*256 + c*16 + h
    int h = bid & 15, c = (bid >> 4) & 15, b = bid >> 8;
    int lr = lane & 15, kb = lane >> 4;

    f16x8 hfrag[4][2];
    const f16* Hh = H16 + (((size_t)((b * 16 + h) * 16 + c)) << 12);
#pragma unroll
    for (int pi = 0; pi < 4; ++pi)
#pragma unroll
        for (int ks = 0; ks < 2; ++ks)
            hfrag[pi][ks] = *(const f16x8*)(Hh + (size_t)(pi * 16 + lr) * 64 + ks * 32 + kb * 8);

    float2 ad = *(const float2*)&dadt[((size_t)(b * 1024 + c * 64 + lane) * 16 + h) * 2];
    float La = ad.x;
#pragma unroll
    for (int o = 1; o < 64; o <<= 1) {
        float v = __shfl_up(La, o);
        if (lane >= o) La += v;
    }
    La64[lane] = La;
    __syncthreads();

    const f16* cp = C16 + (((size_t)(b * 16 + c)) << 12);
    f32x4 acc[4][4];
#pragma unroll
    for (int ti = 0; ti < 4; ++ti)
#pragma unroll
        for (int pi = 0; pi < 4; ++pi) acc[ti][pi] = (f32x4){0.f, 0.f, 0.f, 0.f};
#pragma unroll
    for (int ks = 0; ks < 2; ++ks) {
        f16x8 af[4];
#pragma unroll
        for (int ti = 0; ti < 4; ++ti)
            af[ti] = *(const f16x8*)(cp + (ti * 16 + lr) * 64 + ks * 32 + kb * 8);
#pragma unroll
        for (int ti = 0; ti < 4; ++ti)
#pragma unroll
            for (int pi = 0; pi < 4; ++pi)
                acc[ti][pi] = __builtin_amdgcn_mfma_f32_16x16x32_f16(
                    af[ti], hfrag[pi][ks], acc[ti][pi], 0, 0, 0);
    }
    f16* yp = y2 + ((size_t)(b * 1024 + c * 64)) * 1024 + h * 64;
#pragma unroll
    for (int ti = 0; ti < 4; ++ti)
#pragma unroll
        for (int r = 0; r < 4; ++r) {
            int t = ti * 16 + kb * 4 + r;
            float sc = __expf(La64[t]);
#pragma unroll
            for (int pi = 0; pi < 4; ++pi)
                yp[(size_t)t * 1024 + pi * 16 + lr] = (f16)(sc * acc[ti][pi][r]);
        }
}

// ---- y = (y1 + y2) * silu(z); RMSNorm * rms_w; f16 out for out_proj --------
__global__ __launch_bounds__(256) void k_gate(const f16* __restrict__ zx16,
                                              const float* __restrict__ rmsw,
                                              const f16* __restrict__ y1,
                                              const f16* __restrict__ y2,
                                              f16* __restrict__ ygate) {
    __shared__ float sh[4];
    int bl = blockIdx.x, tid = threadIdx.x;
    int c = tid * 4;
    f16x4 y1v = *reinterpret_cast<const f16x4*>(&y1[(size_t)bl * DINNER + c]);
    f16x4 y2v = *reinterpret_cast<const f16x4*>(&y2[(size_t)bl * DINNER + c]);
    f16x4 z4  = *reinterpret_cast<const f16x4*>(&zx16[(size_t)bl * DINPROJ + c]);
    float v[4];
    float ss = 0.f;
#pragma unroll
    for (int j = 0; j < 4; ++j) {
        v[j] = ((float)y1v[j] + (float)y2v[j]) * silu_f((float)z4[j]);
        ss += v[j] * v[j];
    }
    int lane = tid & 63, wid = tid >> 6;
#pragma unroll
    for (int o = 32; o > 0; o >>= 1) ss += __shfl_down(ss, o, 64);
    if (lane == 0) sh[wid] = ss;
    __syncthreads();
    float total = sh[0] + sh[1] + sh[2] + sh[3];
    float r = rsqrtf(total * (1.f / DINNER) + 1e-5f);
    f16x4 o4;
    o4.x = (f16)(v[0] * r * rmsw[c + 0]);
    o4.y = (f16)(v[1] * r * rmsw[c + 1]);
    o4.z = (f16)(v[2] * r * rmsw[c + 2]);
    o4.w = (f16)(v[3] * r * rmsw[c + 3]);
    *reinterpret_cast<f16x4*>(&ygate[(size_t)bl * DINNER + c]) = o4;
}

// ------- final LayerNorm + mean pool: wave-per-row, block partial, 1 atomic --
__global__ __launch_bounds__(256) void k_lnpool(const f16* __restrict__ h,
                                                const float* __restrict__ lnw,
                                                const float* __restrict__ lnb,
                                                float* __restrict__ pooled) {
    __shared__ float pl[4][256];
    int bid = blockIdx.x;                // 8 * 32
    int b = bid >> 5, seg = bid & 31;
    int tid = threadIdx.x, lane = tid & 63, w = tid >> 6;
    int c4 = lane * 4;
    float4 lw = *(const float4*)&lnw[c4];
    float4 lb = *(const float4*)&lnb[c4];
    float acc0 = 0.f, acc1 = 0.f, acc2 = 0.f, acc3 = 0.f;
    const f16* hb = h + ((size_t)b * 1024 + seg * 32 + w * 8) * DMODEL;
#pragma unroll
    for (int i = 0; i < 8; ++i) {
        f16x4 hv = *(const f16x4*)(hb + (size_t)i * DMODEL + c4);
        float vx = (float)hv.x, vy = (float)hv.y, vz = (float)hv.z, vw = (float)hv.w;
        float s1 = vx + vy + vz + vw;
        float s2 = vx * vx + vy * vy + vz * vz + vw * vw;
#pragma unroll
        for (int o = 32; o > 0; o >>= 1) {
            s1 += __shfl_xor(s1, o);
            s2 += __shfl_xor(s2, o);
        }
        float mu = s1 * (1.f / DMODEL);
        float var = s2 * (1.f / DMODEL) - mu * mu;
        float rr = rsqrtf(var + 1e-5f);
        acc0 += (vx - mu) * rr * lw.x + lb.x;
        acc1 += (vy - mu) * rr * lw.y + lb.y;
        acc2 += (vz - mu) * rr * lw.z + lb.z;
        acc3 += (vw - mu) * rr * lw.w + lb.w;
    }
    pl[w][c4 + 0] = acc0; pl[w][c4 + 1] = acc1;
    pl[w][c4 + 2] = acc2; pl[w][c4 + 3] = acc3;
    __syncthreads();
    float tot = pl[0][tid] + pl[1][tid] + pl[2][tid] + pl[3][tid];
    atomicAdd(&pooled[b * DMODEL + tid], tot * (1.f / LOUT));
}

__global__ void k_zero(float* __restrict__ p, int n) {
    int i = blockIdx.x * 256 + threadIdx.x;
    if (i < n) p[i] = 0.f;
}

// ---------------- regression head ----------------
__global__ __launch_bounds__(128) void k_head(const float* __restrict__ pooled,
                                              const float* __restrict__ w1,
                                              const float* __restrict__ b1,
                                              const float* __restrict__ w2,
                                              const float* __restrict__ b2,
                                              float* __restrict__ out) {
    __shared__ float red[2];
    int b = blockIdx.x, j = threadIdx.x;
    float acc = b1[j];
#pragma unroll 8
    for (int d = 0; d < DMODEL; ++d)
        acc = fmaf(pooled[b * DMODEL + d], w1[j * DMODEL + d], acc);
    float r = gelu_f(acc) * w2[j];
#pragma unroll
    for (int o = 32; o > 0; o >>= 1) r += __shfl_down(r, o, 64);
    int lane = j & 63, wid = j >> 6;
    if (lane == 0) red[wid] = r;
    __syncthreads();
    if (j == 0) out[b] = red[0] + red[1] + b2[0];
}

extern "C" void kernel_launch(void* const* d_in, const int* in_sizes, int n_in,
                              void* d_out, int out_size, void* d_ws, size_t ws_size,
                              hipStream_t stream) {
    const float* x         = (const float*)d_in[0];
    const float* conv1_w   = (const float*)d_in[1];
    const float* conv1_b   = (const float*)d_in[2];
    const float* conv2_w   = (const float*)d_in[3];
    const float* conv2_b   = (const float*)d_in[4];
    const float* in_proj_w = (const float*)d_in[5];
    const float* dw_w      = (const float*)d_in[6];
    const float* dw_b      = (const float*)d_in[7];
    const float* dt_bias   = (const float*)d_in[8];
    const float* A_log     = (const float*)d_in[9];
    const float* ssm_D     = (const float*)d_in[10];
    const float* rms_w     = (const float*)d_in[11];
    const float* out_proj_w= (const float*)d_in[12];
    const float* ln_w      = (const float*)d_in[13];
    const float* ln_b      = (const float*)d_in[14];
    const float* reg1_w    = (const float*)d_in[15];
    const float* reg1_b    = (const float*)d_in[16];
    const float* reg2_w    = (const float*)d_in[17];
    const float* reg2_b    = (const float*)d_in[18];

    float* ws = (float*)d_ws;
    size_t off = 0;
    float* dadt   = ws + off; off += (size_t)NB * LOUT * NHEADS * 2;// 262,144
    float* Abuf   = ws + off; off += (size_t)NB * NHEADS * NCHUNK;  // 2,048
    float* pooled = ws + off; off += NB * DMODEL;                   // 2,048

    f16* fbase = (f16*)(ws + off);
    size_t foff = 0;
    f16* c1f16  = fbase + foff; foff += (size_t)NB * 64 * L1OUT;
    f16* hbf0   = fbase + foff; foff += (size_t)NB * LOUT * DMODEL;
    f16* hbf1   = fbase + foff; foff += (size_t)NB * LOUT * DMODEL;
    f16* ygate  = fbase + foff; foff += (size_t)NB * LOUT * DINNER;   // also H16
    f16* y2     = fbase + foff; foff += (size_t)NB * LOUT * DINNER;
    f16* y1     = fbase + foff; foff += (size_t)NB * LOUT * DINNER;   // also im2h
    f16* C16    = fbase + foff; foff += (size_t)NB * NCHUNK * 64 * 64;
    f16* zx16   = fbase + foff; foff += (size_t)NB * LOUT * DINPROJ;
    f16* Sbuf16 = fbase + foff; foff += (size_t)NB * NHEADS * NCHUNK * 4096;
    f16* w_in_h = fbase + foff; foff += (size_t)NLAYERS * NPADIN * DMODEL;
    f16* w_out_h= fbase + foff; foff += (size_t)NLAYERS * DMODEL * DINNER;
    f16* w_c2_h = fbase + foff; foff += (size_t)DMODEL * 1024;
    f16* H16    = ygate;       // aliased: H16 dead before k_gate writes ygate
    f16* im2h   = y1;          // aliased: im2col dead before y1 first written

    // weight casts
    k_cast_inproj<<<(NLAYERS * NPADIN * 256) / 256, 256, 0, stream>>>(in_proj_w, w_in_h);
    k_cast<<<(NLAYERS * DMODEL * DINNER) / 256, 256, 0, stream>>>(
        out_proj_w, w_out_h, NLAYERS * DMODEL * DINNER);
    k_cast<<<(DMODEL * 1024) / 256, 256, 0, stream>>>(conv2_w, w_c2_h, DMODEL * 1024);

    // front-end convs
    k_conv1<<<(NB * 64 * L1OUT) / 256, 256, 0, stream>>>(x, conv1_w, conv1_b, c1f16);
    k_im2col<<<(NB * LOUT * 1024) / 256, 256, 0, stream>>>(c1f16, im2h);
    {
        dim3 g(256 / 128, 8192 / 64);
        k_hgemm<64, 1><<<g, 256, 0, stream>>>(im2h, w_c2_h, hbf0,
                                              8192, 256, 1024, conv2_b,
                                              nullptr, nullptr, nullptr);
    }

    f16* hcur = hbf0;
    f16* hnxt = hbf1;
    for (int i = 0; i < NLAYERS; ++i) {
        {
            dim3 g(NPADIN / 128, 8192 / 128);
            k_hgemm<128, 2><<<g, 256, 0, stream>>>(
                hcur, w_in_h + (size_t)i * NPADIN * DMODEL, zx16,
                8192, DINPROJ, DMODEL, nullptr,
                dt_bias + i * NHEADS, A_log + i * NHEADS, dadt);
        }
        k_ssd1<<<NB * NCHUNK * 4, 256, 0, stream>>>(
            zx16, dadt, dw_w + (size_t)i * CONVDIM * 4, dw_b + (size_t)i * CONVDIM,
            ssm_D + i * NHEADS, y1, Sbuf16, Abuf, C16);
        k_hscan<<<NB * NHEADS * 4, 64, 0, stream>>>(Sbuf16, Abuf, H16);
        k_ssd2<<<NB * NCHUNK * NHEADS, 64, 0, stream>>>(C16, dadt, H16, y2);
        k_gate<<<NB * LOUT, 256, 0, stream>>>(zx16, rms_w + (size_t)i * DINNER,
                                              y1, y2, ygate);
        {
            dim3 g(DMODEL / 128, 8192 / 64);
            k_hgemm<64, 0><<<g, 256, 0, stream>>>(
                ygate, w_out_h + (size_t)i * DMODEL * DINNER, hnxt,
                8192, DMODEL, DINNER, nullptr, nullptr, nullptr, nullptr);
        }
        f16* tmp = hcur; hcur = hnxt; hnxt = tmp;
    }

    // final LN + pool + head
    k_zero<<<(NB * DMODEL + 255) / 256, 256, 0, stream>>>(pooled, NB * DMODEL);
    k_lnpool<<<NB * 32, 256, 0, stream>>>(hcur, ln_w, ln_b, pooled);
    k_head<<<NB, 128, 0, stream>>>(pooled, reg1_w, reg1_b, reg2_w, reg2_b, (float*)d_out);
}

// Round 9
// 875.889 us; speedup vs baseline: 3.9375x; 1.0782x over previous
//
#include <hip/hip_runtime.h>
#include <math.h>

#define NB       8
#define SEQ      8192
#define L1OUT    2048
#define LOUT     1024
#define DMODEL   256
#define DINNER   1024
#define NHEADS   16
#define HEADDIM  64
#define DSTATE   64
#define CONVDIM  1152
#define DINPROJ  2192
#define NPADIN   2304     // in_proj rows padded to multiple of 128
#define NLAYERS  8
#define NCHUNK   16
#define Q        64       // chunk length

typedef _Float16 f16;
typedef __attribute__((ext_vector_type(8))) _Float16 f16x8;
typedef __attribute__((ext_vector_type(4))) _Float16 f16x4;
typedef __attribute__((ext_vector_type(4))) float    f32x4;

__device__ __forceinline__ float gelu_f(float v) {
    return 0.5f * v * (1.0f + erff(v * 0.70710678118654752f));
}
__device__ __forceinline__ float silu_f(float v) {
    return v * __builtin_amdgcn_rcpf(1.0f + __expf(-v));
}

__device__ __forceinline__ void gload16(const void* g, void* l) {
    __builtin_amdgcn_global_load_lds(
        (const __attribute__((address_space(1))) unsigned int*)g,
        (__attribute__((address_space(3))) unsigned int*)l, 16, 0, 0);
}

// ---------------- weight casts ----------------
__global__ __launch_bounds__(256) void k_cast(const float* __restrict__ in,
                                              f16* __restrict__ out, int n) {
    int i = blockIdx.x * 256 + threadIdx.x;
    if (i < n) out[i] = (f16)in[i];
}

__global__ __launch_bounds__(256) void k_cast_inproj(const float* __restrict__ w,
                                                     f16* __restrict__ out) {
    int idx = blockIdx.x * 256 + threadIdx.x;       // 8*2304*256
    int c = idx & 255;
    int r = (idx >> 8) % NPADIN;
    int l = idx / (NPADIN * 256);
    float v = (r < DINPROJ) ? w[((size_t)l * DINPROJ + r) * 256 + c] : 0.f;
    out[idx] = (f16)v;
}

// ------- conv1 (3->64, k16, s4, pad6) + GELU -> f16, 8 outputs/thread -------
__global__ __launch_bounds__(256) void k_conv1(const float* __restrict__ x,
                                               const float* __restrict__ w,
                                               const float* __restrict__ bias,
                                               f16* __restrict__ out) {
    int idx = blockIdx.x * 256 + threadIdx.x;      // NB*64*256 = 131072
    int u  = idx & 255;                            // 8-output group
    int co = (idx >> 8) & 63;
    int b  = idx >> 14;
    int xbase = u * 32 - 8;

    float acc[8];
#pragma unroll
    for (int t = 0; t < 8; ++t) acc[t] = bias[co];

#pragma unroll
    for (int ci = 0; ci < 3; ++ci) {
        const float* xp = x + ((size_t)b * 3 + ci) * SEQ;
        float xb[48];
#pragma unroll
        for (int j = 0; j < 12; ++j) {
            int off = xbase + j * 4;
            float4 v;
            if (off >= 0 && off + 3 < SEQ) {
                v = *(const float4*)&xp[off];
            } else {
                v.x = (off + 0 >= 0 && off + 0 < SEQ) ? xp[off + 0] : 0.f;
                v.y = (off + 1 >= 0 && off + 1 < SEQ) ? xp[off + 1] : 0.f;
                v.z = (off + 2 >= 0 && off + 2 < SEQ) ? xp[off + 2] : 0.f;
                v.w = (off + 3 >= 0 && off + 3 < SEQ) ? xp[off + 3] : 0.f;
            }
            xb[j * 4 + 0] = v.x; xb[j * 4 + 1] = v.y;
            xb[j * 4 + 2] = v.z; xb[j * 4 + 3] = v.w;
        }
        const float* wp = w + (co * 3 + ci) * 16;
        float wv[16];
#pragma unroll
        for (int k = 0; k < 16; ++k) wv[k] = wp[k];
#pragma unroll
        for (int t = 0; t < 8; ++t)
#pragma unroll
            for (int k = 0; k < 16; ++k)
                acc[t] = fmaf(xb[t * 4 + k + 2], wv[k], acc[t]);
    }
    f16x8 o;
#pragma unroll
    for (int t = 0; t < 8; ++t) o[t] = (f16)gelu_f(acc[t]);
    *(f16x8*)&out[((size_t)(b * 64 + co)) * L1OUT + u * 8] = o;
}

// ------- im2col for conv2 (64ch, k16, s2, pad7), vectorized stores ----------
__global__ __launch_bounds__(256) void k_im2col(const f16* __restrict__ h1,
                                                f16* __restrict__ A) {
    int idx = blockIdx.x * 256 + threadIdx.x;      // 8192*128
    int g = idx & 127;
    int row = idx >> 7;
    int t = row & (LOUT - 1);
    int b = row >> 10;
    int ci = g >> 1, k0 = (g & 1) * 8;
    int pos0 = t * 2 + k0 - 7;
    const f16* hp = h1 + ((size_t)(b * 64 + ci)) * L1OUT;
    f16x8 v;
#pragma unroll
    for (int j = 0; j < 8; ++j) {
        int p = pos0 + j;
        v[j] = (p >= 0 && p < L1OUT) ? hp[p] : (f16)0.f;
    }
    *(f16x8*)&A[(size_t)row * 1024 + g * 8] = v;
}

// ---------------- fp16 MFMA GEMM: C[M,N] = A[M,K] * B[Npad,K]^T --------------
// BK=64, XOR-swizzled LDS (source-side swizzle + swizzled ds_read).
// EPI 0: plain f16; 1: gelu(v+bias); 2: f16 + dt cols -> dadt.
template<int BM, int EPI>
__global__ __launch_bounds__(256) void k_hgemm(const f16* __restrict__ A,
                                               const f16* __restrict__ Bw,
                                               f16* __restrict__ Ch,
                                               int M, int N, int K,
                                               const float* __restrict__ bias,
                                               const float* __restrict__ dt_bias,
                                               const float* __restrict__ A_log,
                                               float* __restrict__ dadt) {
    constexpr int MI = BM / 32;
    __shared__ f16 As[BM * 64];
    __shared__ f16 Bs[128 * 64];
    int tid  = threadIdx.x;
    int lane = tid & 63, wid = tid >> 6;
    int wm = wid >> 1, wn = wid & 1;
    int row0 = blockIdx.y * BM, col0 = blockIdx.x * 128;
    int lr = lane & 15, kb = lane >> 4;

    f32x4 acc[MI][4];
#pragma unroll
    for (int mi = 0; mi < MI; ++mi)
#pragma unroll
        for (int ni = 0; ni < 4; ++ni)
            acc[mi][ni] = (f32x4){0.f, 0.f, 0.f, 0.f};

    int sr  = tid >> 3;                         // 0..31 staging row
    int scx = ((tid & 7) ^ (sr & 7)) * 8;       // swizzled col (f16)
    int rsw = (lr & 7) * 8;                     // read-side XOR (f16)

    for (int k0 = 0; k0 < K; k0 += 64) {
        __syncthreads();
#pragma unroll
        for (int is = 0; is < BM / 32; ++is)
            gload16(A + (size_t)(row0 + is * 32 + sr) * K + k0 + scx,
                    &As[is * 2048 + wid * 512]);
#pragma unroll
        for (int is = 0; is < 4; ++is)
            gload16(Bw + (size_t)(col0 + is * 32 + sr) * K + k0 + scx,
                    &Bs[is * 2048 + wid * 512]);
        __syncthreads();

#pragma unroll
        for (int ks = 0; ks < 2; ++ks) {
            int cbase = (ks * 32 + kb * 8) ^ rsw;
            f16x8 a[MI], b[4];
#pragma unroll
            for (int mi = 0; mi < MI; ++mi)
                a[mi] = *reinterpret_cast<const f16x8*>(
                    &As[(wm * (BM / 2) + mi * 16 + lr) * 64 + cbase]);
#pragma unroll
            for (int ni = 0; ni < 4; ++ni)
                b[ni] = *reinterpret_cast<const f16x8*>(
                    &Bs[(wn * 64 + ni * 16 + lr) * 64 + cbase]);
#pragma unroll
            for (int mi = 0; mi < MI; ++mi)
#pragma unroll
                for (int ni = 0; ni < 4; ++ni)
                    acc[mi][ni] = __builtin_amdgcn_mfma_f32_16x16x32_f16(
                        a[mi], b[ni], acc[mi][ni], 0, 0, 0);
        }
    }

#pragma unroll
    for (int mi = 0; mi < MI; ++mi)
#pragma unroll
        for (int ni = 0; ni < 4; ++ni) {
            int ccol = col0 + wn * 64 + ni * 16 + lr;
            if (ccol < N) {
                int rbase = row0 + wm * (BM / 2) + mi * 16 + kb * 4;
                f32x4 v = acc[mi][ni];
#pragma unroll
                for (int r = 0; r < 4; ++r) {
                    float val = v[r];
                    if (EPI == 1) val = gelu_f(val + bias[ccol]);
                    Ch[(size_t)(rbase + r) * N + ccol] = (f16)val;
                    if (EPI == 2 && ccol >= DINNER + CONVDIM) {
                        int hh = ccol - (DINNER + CONVDIM);
                        float raw = val + dt_bias[hh];
                        float dtv = (raw > 20.f) ? raw : log1pf(__expf(raw));
                        float lda = -__expf(A_log[hh]) * dtv;
                        *(float2*)&dadt[(size_t)(rbase + r) * 32 + hh * 2] =
                            make_float2(lda, dtv);
                    }
                }
            }
        }
}

// ---------------- SSD part 1: per (b, chunk, 4 heads) ----------------
// Fused depthwise conv+SiLU staging of B/C/X from zx16; G = C.B^T;
// per head: S = X^T.(w*B)^T (f16), M = masked decay*G (+D on diag),
// Y_intra = M.X -> y1 (f16). hq==0 also writes conv'd C to C16 for ssd2.
__global__ __launch_bounds__(256) void k_ssd1(const f16* __restrict__ zx16,
                                              const float* __restrict__ dadt,
                                              const float* __restrict__ dw_w,
                                              const float* __restrict__ dw_b,
                                              const float* __restrict__ ssmD,
                                              f16* __restrict__ y1,
                                              f16* __restrict__ Sbuf16,
                                              float* __restrict__ Abuf,
                                              f16* __restrict__ C16) {
    __shared__ f16 Bs[64][72];
    __shared__ f16 Cs[64][72];
    __shared__ float GT[64][68];            // GT[s][t]
    __shared__ f16 Mw[4][64][72];           // X staging, then per-wave sBT / M
    __shared__ float2 LaDt[4][64];

    int tid = threadIdx.x, lane = tid & 63, wid = tid >> 6;
    int bid = blockIdx.x;
    int hq = bid & 3, c = (bid >> 2) & 15, b = bid >> 6;
    int h = hq * 4 + wid;
    int lr = lane & 15, kb = lane >> 4;
    f16* Xs = &Mw[0][0][0];                 // [64][260] f16 (33,280 B)

    // ---- fused conv+SiLU staging: threads 0..191 own (ch-group, 16-t slice)
    {
        int sg = tid % 48;                  // 0..31 X, 32..39 B, 40..47 C
        int ts = tid / 48;                  // t-slice (use 0..3)
        if (ts < 4) {
            int xc;                         // xbc-channel base (weight index)
            if (sg < 32)      xc = hq * 256 + sg * 8;
            else if (sg < 40) xc = 1024 + (sg - 32) * 8;
            else              xc = 1088 + (sg - 40) * 8;
            int zc = 1024 + xc;             // zx16 column
            float4 wv[8];
            float  bv[8];
#pragma unroll
            for (int j = 0; j < 8; ++j) {
                wv[j] = *(const float4*)&dw_w[(xc + j) * 4];
                bv[j] = dw_b[xc + j];
            }
            int l0 = c * 64 + ts * 16;      // in-batch row of first output
            const f16* zrow = zx16 + ((size_t)(b * 1024 + l0)) * DINPROJ + zc;
            f16x8 r0, r1, r2, r3;
            f16x8 zz;
#pragma unroll
            for (int j = 0; j < 8; ++j) zz[j] = (f16)0.f;
            r0 = (l0 >= 3) ? *(const f16x8*)(zrow - 3 * DINPROJ) : zz;
            r1 = (l0 >= 2) ? *(const f16x8*)(zrow - 2 * DINPROJ) : zz;
            r2 = (l0 >= 1) ? *(const f16x8*)(zrow - 1 * DINPROJ) : zz;
#pragma unroll
            for (int t = 0; t < 16; ++t) {
                r3 = *(const f16x8*)(zrow + t * DINPROJ);
                f16x8 o;
#pragma unroll
                for (int j = 0; j < 8; ++j) {
                    float s = bv[j];
                    s = fmaf((float)r0[j], wv[j].x, s);
                    s = fmaf((float)r1[j], wv[j].y, s);
                    s = fmaf((float)r2[j], wv[j].z, s);
                    s = fmaf((float)r3[j], wv[j].w, s);
                    o[j] = (f16)silu_f(s);
                }
                int row = ts * 16 + t;
                if (sg < 32) {
                    f16x4 o0 = {o[0], o[1], o[2], o[3]};
                    f16x4 o1 = {o[4], o[5], o[6], o[7]};
                    *(f16x4*)&Xs[row * 260 + sg * 8]     = o0;
                    *(f16x4*)&Xs[row * 260 + sg * 8 + 4] = o1;
                } else if (sg < 40) {
                    *(f16x8*)&Bs[row][(sg - 32) * 8] = o;
                } else {
                    *(f16x8*)&Cs[row][(sg - 40) * 8] = o;
                }
                r0 = r1; r1 = r2; r2 = r3;
            }
        }
    }

    // per-lane (lane = t): log-decay cumsum + dt (independent of staging)
    float2 ad = *(const float2*)&dadt[((size_t)(b * 1024 + c * 64 + lane) * 16 + h) * 2];
    float La = ad.x;
#pragma unroll
    for (int o = 1; o < 64; o <<= 1) {
        float v = __shfl_up(La, o);
        if (lane >= o) La += v;
    }
    float dt_own = ad.y;
    float La63 = __shfl(La, 63);
    float w_own = __expf(La63 - La) * dt_own;   // state weight, <= dt
    LaDt[wid][lane] = make_float2(La, dt_own);
    float Dh = ssmD[h];
    __syncthreads();

    // export conv'd C for ssd2 (one hq per (b,c))
    if (hq == 0) {
        f16* cp = C16 + (((size_t)(b * 16 + c)) << 12);
#pragma unroll
        for (int it = 0; it < 2; ++it) {
            int cid = it * 256 + tid;
            int row = cid >> 3, off = (cid & 7) * 8;
            *(f16x8*)&cp[row * 64 + off] = *(const f16x8*)&Cs[row][off];
        }
    }

    // read X^T fragments from LDS (row p, k=t)
    f16x8 xfrag[4][2];
#pragma unroll
    for (int pi = 0; pi < 4; ++pi)
#pragma unroll
        for (int ks = 0; ks < 2; ++ks) {
            f16x8 v;
#pragma unroll
            for (int j = 0; j < 8; ++j)
                v[j] = Xs[(ks * 32 + kb * 8 + j) * 260 + wid * 64 + pi * 16 + lr];
            xfrag[pi][ks] = v;
        }

    // G = C.B^T : each wave one 32x32 quadrant -> GT[s][t]
    {
        int tq = wid & 1, sq = wid >> 1;
        f32x4 g[2][2];
#pragma unroll
        for (int i = 0; i < 2; ++i)
#pragma unroll
            for (int j = 0; j < 2; ++j) g[i][j] = (f32x4){0.f, 0.f, 0.f, 0.f};
#pragma unroll
        for (int ks = 0; ks < 2; ++ks) {
            f16x8 a[2], bb[2];
#pragma unroll
            for (int ti = 0; ti < 2; ++ti)
                a[ti] = *(const f16x8*)&Cs[tq * 32 + ti * 16 + lr][ks * 32 + kb * 8];
#pragma unroll
            for (int si = 0; si < 2; ++si)
                bb[si] = *(const f16x8*)&Bs[sq * 32 + si * 16 + lr][ks * 32 + kb * 8];
#pragma unroll
            for (int ti = 0; ti < 2; ++ti)
#pragma unroll
                for (int si = 0; si < 2; ++si)
                    g[ti][si] = __builtin_amdgcn_mfma_f32_16x16x32_f16(
                        a[ti], bb[si], g[ti][si], 0, 0, 0);
        }
#pragma unroll
        for (int ti = 0; ti < 2; ++ti)
#pragma unroll
            for (int si = 0; si < 2; ++si)
#pragma unroll
                for (int r = 0; r < 4; ++r)
                    GT[sq * 32 + si * 16 + lr][tq * 32 + ti * 16 + kb * 4 + r] = g[ti][si][r];
    }
    __syncthreads();   // GT ready; all xfrag reads done -> Mw reusable

    // ---- head phase (wave-local) ----
    // sBT[n][t] = B[t][n] * w_t  into Mw[wid]
    {
        f16x8 brow[8];
#pragma unroll
        for (int i = 0; i < 8; ++i) brow[i] = *(const f16x8*)&Bs[lane][i * 8];
#pragma unroll
        for (int i = 0; i < 8; ++i)
#pragma unroll
            for (int j = 0; j < 8; ++j)
                Mw[wid][i * 8 + j][lane] = (f16)((float)brow[i][j] * w_own);
    }
    __builtin_amdgcn_wave_barrier();

    f16x8 sbfrag[4][2];
#pragma unroll
    for (int ni = 0; ni < 4; ++ni)
#pragma unroll
        for (int ks = 0; ks < 2; ++ks)
            sbfrag[ni][ks] = *(const f16x8*)&Mw[wid][ni * 16 + lr][ks * 32 + kb * 8];

    // S[p][n] = sum_t X^T[p][t] sBT[n][t]  -> f16
    {
        f32x4 accS[4][4];
#pragma unroll
        for (int pi = 0; pi < 4; ++pi)
#pragma unroll
            for (int ni = 0; ni < 4; ++ni) accS[pi][ni] = (f32x4){0.f, 0.f, 0.f, 0.f};
#pragma unroll
        for (int ks = 0; ks < 2; ++ks)
#pragma unroll
            for (int pi = 0; pi < 4; ++pi)
#pragma unroll
                for (int ni = 0; ni < 4; ++ni)
                    accS[pi][ni] = __builtin_amdgcn_mfma_f32_16x16x32_f16(
                        xfrag[pi][ks], sbfrag[ni][ks], accS[pi][ni], 0, 0, 0);
        size_t sbase = ((size_t)((b * 16 + h) * 16 + c)) << 12;
#pragma unroll
        for (int pi = 0; pi < 4; ++pi)
#pragma unroll
            for (int ni = 0; ni < 4; ++ni)
#pragma unroll
                for (int r = 0; r < 4; ++r)
                    Sbuf16[sbase + (size_t)(pi * 16 + kb * 4 + r) * 64 + ni * 16 + lr] =
                        (f16)accS[pi][ni][r];
        if (lane == 0) Abuf[(b * 16 + h) * 16 + c] = __expf(La63);
    }
    __builtin_amdgcn_wave_barrier();

    // M[t][s] = (s<=t) ? G[t][s]*exp(La_t-La_s)*dt_s : 0 ; M[t][t] += D_h
    {
        int t = lane;
        float la_t = La;
#pragma unroll
        for (int s8 = 0; s8 < 8; ++s8) {
            f16x8 mv;
#pragma unroll
            for (int j = 0; j < 8; ++j) {
                int s = s8 * 8 + j;
                float2 ld = LaDt[wid][s];
                float m = (s <= t) ? GT[s][t] * __expf(la_t - ld.x) * ld.y : 0.f;
                if (s == t) m += Dh;
                mv[j] = (f16)m;
            }
            *(f16x8*)&Mw[wid][t][s8 * 8] = mv;
        }
    }
    __builtin_amdgcn_wave_barrier();

    // Y_intra[t][p] = sum_s M[t][s] X[s][p]  -> f16 (includes D*xh)
    {
        f32x4 accY[4][4];
#pragma unroll
        for (int ti = 0; ti < 4; ++ti)
#pragma unroll
            for (int pi = 0; pi < 4; ++pi) accY[ti][pi] = (f32x4){0.f, 0.f, 0.f, 0.f};
#pragma unroll
        for (int ks = 0; ks < 2; ++ks) {
            f16x8 af[4];
#pragma unroll
            for (int ti = 0; ti < 4; ++ti)
                af[ti] = *(const f16x8*)&Mw[wid][ti * 16 + lr][ks * 32 + kb * 8];
#pragma unroll
            for (int ti = 0; ti < 4; ++ti)
#pragma unroll
                for (int pi = 0; pi < 4; ++pi)
                    accY[ti][pi] = __builtin_amdgcn_mfma_f32_16x16x32_f16(
                        af[ti], xfrag[pi][ks], accY[ti][pi], 0, 0, 0);
        }
        f16* yp = y1 + ((size_t)(b * 1024 + c * 64)) * 1024 + h * 64;
#pragma unroll
        for (int ti = 0; ti < 4; ++ti)
#pragma unroll
            for (int pi = 0; pi < 4; ++pi)
#pragma unroll
                for (int r = 0; r < 4; ++r)
                    yp[(size_t)(ti * 16 + kb * 4 + r) * 1024 + pi * 16 + lr] =
                        (f16)accY[ti][pi][r];
    }
}

// ------- fused inter-chunk recurrence + SSD part 2: one block per (b,h) -----
// Phase 1: 256 threads run the 16-chunk state recurrence, H inits -> LDS
// (XOR-swizzled rows). Phase 2: wave w handles 4 chunks' y2 = exp(La)*(C.H^T).
__global__ __launch_bounds__(256) void k_ssd2f(const f16* __restrict__ C16,
                                               const f16* __restrict__ Sbuf16,
                                               const float* __restrict__ Abuf,
                                               const float* __restrict__ dadt,
                                               f16* __restrict__ y2) {
    __shared__ f16 Hs[NCHUNK][4096];      // 128 KiB
    int tid = threadIdx.x, lane = tid & 63, wv = tid >> 6;
    int bh = blockIdx.x;
    int h = bh & 15, b = bh >> 4;
    int lr = lane & 15, kb = lane >> 4;
    size_t base = (size_t)bh << 16;

    // phase 1: recurrence, write swizzled H-init per chunk
    {
        int off = tid * 16;
        int row = tid >> 2;
        int c0f = (tid & 3) * 16;
        int sw = (row & 7) * 8;
        int d0 = row * 64 + (c0f ^ sw);
        int d1 = row * 64 + ((c0f + 8) ^ sw);
        float Hl[16];
#pragma unroll
        for (int j = 0; j < 16; ++j) Hl[j] = 0.f;
#pragma unroll
        for (int c = 0; c < NCHUNK; ++c) {
            f16x8 o0, o1;
#pragma unroll
            for (int j = 0; j < 8; ++j) { o0[j] = (f16)Hl[j]; o1[j] = (f16)Hl[j + 8]; }
            *(f16x8*)&Hs[c][d0] = o0;
            *(f16x8*)&Hs[c][d1] = o1;
            float A = Abuf[bh * 16 + c];
            f16x8 s0 = *(const f16x8*)&Sbuf16[base + (size_t)c * 4096 + off];
            f16x8 s1 = *(const f16x8*)&Sbuf16[base + (size_t)c * 4096 + off + 8];
#pragma unroll
            for (int j = 0; j < 8; ++j) {
                Hl[j]     = fmaf(Hl[j],     A, (float)s0[j]);
                Hl[j + 8] = fmaf(Hl[j + 8], A, (float)s1[j]);
            }
        }
    }
    __syncthreads();

    // phase 2
    const f16* cpb = C16 + ((size_t)b << 16);
#pragma unroll
    for (int i = 0; i < 4; ++i) {
        int c = wv * 4 + i;
        float2 ad = *(const float2*)&dadt[((size_t)(b * 1024 + c * 64 + lane) * 16 + h) * 2];
        float La = ad.x;
#pragma unroll
        for (int o = 1; o < 64; o <<= 1) {
            float v = __shfl_up(La, o);
            if (lane >= o) La += v;
        }

        f16x8 hfrag[4][2];
#pragma unroll
        for (int pi = 0; pi < 4; ++pi)
#pragma unroll
            for (int ks = 0; ks < 2; ++ks) {
                int row = pi * 16 + lr;
                int cf = (ks * 32 + kb * 8) ^ ((row & 7) * 8);
                hfrag[pi][ks] = *(const f16x8*)&Hs[c][row * 64 + cf];
            }

        const f16* cp = cpb + ((size_t)c << 12);
        f32x4 acc[4][4];
#pragma unroll
        for (int ti = 0; ti < 4; ++ti)
#pragma unroll
            for (int pi = 0; pi < 4; ++pi) acc[ti][pi] = (f32x4){0.f, 0.f, 0.f, 0.f};
#pragma unroll
        for (int ks = 0; ks < 2; ++ks) {
            f16x8 af[4];
#pragma unroll
            for (int ti = 0; ti < 4; ++ti)
                af[ti] = *(const f16x8*)(cp + (ti * 16 + lr) * 64 + ks * 32 + kb * 8);
#pragma unroll
            for (int ti = 0; ti < 4; ++ti)
#pragma unroll
                for (int pi = 0; pi < 4; ++pi)
                    acc[ti][pi] = __builtin_amdgcn_mfma_f32_16x16x32_f16(
                        af[ti], hfrag[pi][ks], acc[ti][pi], 0, 0, 0);
        }
        f16* yp = y2 + ((size_t)(b * 1024 + c * 64)) * 1024 + h * 64;
#pragma unroll
        for (int ti = 0; ti < 4; ++ti)
#pragma unroll
            for (int r = 0; r < 4; ++r) {
                int t = ti * 16 + kb * 4 + r;
                float sc = __expf(__shfl(La, t));
#pragma unroll
                for (int pi = 0; pi < 4; ++pi)
                    yp[(size_t)t * 1024 + pi * 16 + lr] = (f16)(sc * acc[ti][pi][r]);
            }
    }
}

// ---- y = (y1 + y2) * silu(z); RMSNorm * rms_w; f16 out for out_proj --------
__global__ __launch_bounds__(256) void k_gate(const f16* __restrict__ zx16,
                                              const float* __restrict__ rmsw,
                                              const f16* __restrict__ y1,
                                              const f16* __restrict__ y2,
                                              f16* __restrict__ ygate) {
    __shared__ float sh[4];
    int bl = blockIdx.x, tid = threadIdx.x;
    int c = tid * 4;
    f16x4 y1v = *reinterpret_cast<const f16x4*>(&y1[(size_t)bl * DINNER + c]);
    f16x4 y2v = *reinterpret_cast<const f16x4*>(&y2[(size_t)bl * DINNER + c]);
    f16x4 z4  = *reinterpret_cast<const f16x4*>(&zx16[(size_t)bl * DINPROJ + c]);
    float v[4];
    float ss = 0.f;
#pragma unroll
    for (int j = 0; j < 4; ++j) {
        v[j] = ((float)y1v[j] + (float)y2v[j]) * silu_f((float)z4[j]);
        ss += v[j] * v[j];
    }
    int lane = tid & 63, wid = tid >> 6;
#pragma unroll
    for (int o = 32; o > 0; o >>= 1) ss += __shfl_down(ss, o, 64);
    if (lane == 0) sh[wid] = ss;
    __syncthreads();
    float total = sh[0] + sh[1] + sh[2] + sh[3];
    float r = rsqrtf(total * (1.f / DINNER) + 1e-5f);
    f16x4 o4;
    o4.x = (f16)(v[0] * r * rmsw[c + 0]);
    o4.y = (f16)(v[1] * r * rmsw[c + 1]);
    o4.z = (f16)(v[2] * r * rmsw[c + 2]);
    o4.w = (f16)(v[3] * r * rmsw[c + 3]);
    *reinterpret_cast<f16x4*>(&ygate[(size_t)bl * DINNER + c]) = o4;
}

// -- final LayerNorm + mean pool: wave-per-row, per-(b,seg) partial (no atomic)
__global__ __launch_bounds__(256) void k_lnpool(const f16* __restrict__ h,
                                                const float* __restrict__ lnw,
                                                const float* __restrict__ lnb,
                                                float* __restrict__ pooledp) {
    __shared__ float pl[4][256];
    int bid = blockIdx.x;                // 8 * 32
    int b = bid >> 5, seg = bid & 31;
    int tid = threadIdx.x, lane = tid & 63, w = tid >> 6;
    int c4 = lane * 4;
    float4 lw = *(const float4*)&lnw[c4];
    float4 lb = *(const float4*)&lnb[c4];
    float acc0 = 0.f, acc1 = 0.f, acc2 = 0.f, acc3 = 0.f;
    const f16* hb = h + ((size_t)b * 1024 + seg * 32 + w * 8) * DMODEL;
#pragma unroll
    for (int i = 0; i < 8; ++i) {
        f16x4 hv = *(const f16x4*)(hb + (size_t)i * DMODEL + c4);
        float vx = (float)hv.x, vy = (float)hv.y, vz = (float)hv.z, vw = (float)hv.w;
        float s1 = vx + vy + vz + vw;
        float s2 = vx * vx + vy * vy + vz * vz + vw * vw;
#pragma unroll
        for (int o = 32; o > 0; o >>= 1) {
            s1 += __shfl_xor(s1, o);
            s2 += __shfl_xor(s2, o);
        }
        float mu = s1 * (1.f / DMODEL);
        float var = s2 * (1.f / DMODEL) - mu * mu;
        float rr = rsqrtf(var + 1e-5f);
        acc0 += (vx - mu) * rr * lw.x + lb.x;
        acc1 += (vy - mu) * rr * lw.y + lb.y;
        acc2 += (vz - mu) * rr * lw.z + lb.z;
        acc3 += (vw - mu) * rr * lw.w + lb.w;
    }
    pl[w][c4 + 0] = acc0; pl[w][c4 + 1] = acc1;
    pl[w][c4 + 2] = acc2; pl[w][c4 + 3] = acc3;
    __syncthreads();
    float tot = pl[0][tid] + pl[1][tid] + pl[2][tid] + pl[3][tid];
    pooledp[(size_t)(b * 32 + seg) * 256 + tid] = tot;
}

// ---------------- regression head (reduces 32 partials) ----------------
__global__ __launch_bounds__(128) void k_head(const float* __restrict__ pooledp,
                                              const float* __restrict__ w1,
                                              const float* __restrict__ b1,
                                              const float* __restrict__ w2,
                                              const float* __restrict__ b2,
                                              float* __restrict__ out) {
    __shared__ float sp[256];
    __shared__ float red[2];
    int b = blockIdx.x, j = threadIdx.x;
    for (int d = j; d < 256; d += 128) {
        float s = 0.f;
#pragma unroll
        for (int seg = 0; seg < 32; ++seg)
            s += pooledp[(size_t)(b * 32 + seg) * 256 + d];
        sp[d] = s * (1.f / LOUT);
    }
    __syncthreads();
    float acc = b1[j];
#pragma unroll 8
    for (int d = 0; d < DMODEL; ++d)
        acc = fmaf(sp[d], w1[j * DMODEL + d], acc);
    float r = gelu_f(acc) * w2[j];
#pragma unroll
    for (int o = 32; o > 0; o >>= 1) r += __shfl_down(r, o, 64);
    int lane = j & 63, wid = j >> 6;
    if (lane == 0) red[wid] = r;
    __syncthreads();
    if (j == 0) out[b] = red[0] + red[1] + b2[0];
}

extern "C" void kernel_launch(void* const* d_in, const int* in_sizes, int n_in,
                              void* d_out, int out_size, void* d_ws, size_t ws_size,
                              hipStream_t stream) {
    const float* x         = (const float*)d_in[0];
    const float* conv1_w   = (const float*)d_in[1];
    const float* conv1_b   = (const float*)d_in[2];
    const float* conv2_w   = (const float*)d_in[3];
    const float* conv2_b   = (const float*)d_in[4];
    const float* in_proj_w = (const float*)d_in[5];
    const float* dw_w      = (const float*)d_in[6];
    const float* dw_b      = (const float*)d_in[7];
    const float* dt_bias   = (const float*)d_in[8];
    const float* A_log     = (const float*)d_in[9];
    const float* ssm_D     = (const float*)d_in[10];
    const float* rms_w     = (const float*)d_in[11];
    const float* out_proj_w= (const float*)d_in[12];
    const float* ln_w      = (const float*)d_in[13];
    const float* ln_b      = (const float*)d_in[14];
    const float* reg1_w    = (const float*)d_in[15];
    const float* reg1_b    = (const float*)d_in[16];
    const float* reg2_w    = (const float*)d_in[17];
    const float* reg2_b    = (const float*)d_in[18];

    float* ws = (float*)d_ws;
    size_t off = 0;
    float* dadt    = ws + off; off += (size_t)NB * LOUT * NHEADS * 2; // 262,144
    float* Abuf    = ws + off; off += (size_t)NB * NHEADS * NCHUNK;   // 2,048
    float* pooledp = ws + off; off += (size_t)NB * 32 * 256;          // 65,536

    f16* fbase = (f16*)(ws + off);
    size_t foff = 0;
    f16* c1f16  = fbase + foff; foff += (size_t)NB * 64 * L1OUT;
    f16* hbf0   = fbase + foff; foff += (size_t)NB * LOUT * DMODEL;
    f16* hbf1   = fbase + foff; foff += (size_t)NB * LOUT * DMODEL;
    f16* ygate  = fbase + foff; foff += (size_t)NB * LOUT * DINNER;
    f16* y2     = fbase + foff; foff += (size_t)NB * LOUT * DINNER;
    f16* y1     = fbase + foff; foff += (size_t)NB * LOUT * DINNER;   // also im2h
    f16* C16    = fbase + foff; foff += (size_t)NB * NCHUNK * 64 * 64;
    f16* zx16   = fbase + foff; foff += (size_t)NB * LOUT * DINPROJ;
    f16* Sbuf16 = fbase + foff; foff += (size_t)NB * NHEADS * NCHUNK * 4096;
    f16* w_in_h = fbase + foff; foff += (size_t)NLAYERS * NPADIN * DMODEL;
    f16* w_out_h= fbase + foff; foff += (size_t)NLAYERS * DMODEL * DINNER;
    f16* w_c2_h = fbase + foff; foff += (size_t)DMODEL * 1024;
    f16* im2h   = y1;          // aliased: im2col dead before y1 first written

    // weight casts
    k_cast_inproj<<<(NLAYERS * NPADIN * 256) / 256, 256, 0, stream>>>(in_proj_w, w_in_h);
    k_cast<<<(NLAYERS * DMODEL * DINNER) / 256, 256, 0, stream>>>(
        out_proj_w, w_out_h, NLAYERS * DMODEL * DINNER);
    k_cast<<<(DMODEL * 1024) / 256, 256, 0, stream>>>(conv2_w, w_c2_h, DMODEL * 1024);

    // front-end convs
    k_conv1<<<(NB * 64 * 256) / 256, 256, 0, stream>>>(x, conv1_w, conv1_b, c1f16);
    k_im2col<<<(NB * LOUT * 128) / 256, 256, 0, stream>>>(c1f16, im2h);
    {
        dim3 g(256 / 128, 8192 / 64);
        k_hgemm<64, 1><<<g, 256, 0, stream>>>(im2h, w_c2_h, hbf0,
                                              8192, 256, 1024, conv2_b,
                                              nullptr, nullptr, nullptr);
    }

    f16* hcur = hbf0;
    f16* hnxt = hbf1;
    for (int i = 0; i < NLAYERS; ++i) {
        {
            dim3 g(NPADIN / 128, 8192 / 128);
            k_hgemm<128, 2><<<g, 256, 0, stream>>>(
                hcur, w_in_h + (size_t)i * NPADIN * DMODEL, zx16,
                8192, DINPROJ, DMODEL, nullptr,
                dt_bias + i * NHEADS, A_log + i * NHEADS, dadt);
        }
        k_ssd1<<<NB * NCHUNK * 4, 256, 0, stream>>>(
            zx16, dadt, dw_w + (size_t)i * CONVDIM * 4, dw_b + (size_t)i * CONVDIM,
            ssm_D + i * NHEADS, y1, Sbuf16, Abuf, C16);
        k_ssd2f<<<NB * NHEADS, 256, 0, stream>>>(C16, Sbuf16, Abuf, dadt, y2);
        k_gate<<<NB * LOUT, 256, 0, stream>>>(zx16, rms_w + (size_t)i * DINNER,
                                              y1, y2, ygate);
        {
            dim3 g(DMODEL / 128, 8192 / 64);
            k_hgemm<64, 0><<<g, 256, 0, stream>>>(
                ygate, w_out_h + (size_t)i * DMODEL * DINNER, hnxt,
                8192, DMODEL, DINNER, nullptr, nullptr, nullptr, nullptr);
        }
        f16* tmp = hcur; hcur = hnxt; hnxt = tmp;
    }

    // final LN + pool + head
    k_lnpool<<<NB * 32, 256, 0, stream>>>(hcur, ln_w, ln_b, pooledp);
    k_head<<<NB, 128, 0, stream>>>(pooledp, reg1_w, reg1_b, reg2_w, reg2_b, (float*)d_out);
}